// Round 2
// baseline (808.928 us; speedup 1.0000x reference)
//
#include <hip/hip_runtime.h>
#include <cstdint>

#define DEV __device__ __forceinline__

DEV float sigmoidf_(float x){ return 1.f / (1.f + __expf(-x)); }
DEV float siluf_(float x){ return x * sigmoidf_(x); }
DEV float softplusf_(float x){ return x > 20.f ? x : log1pf(__expf(x)); }
DEV float lreluf_(float x){ return x >= 0.f ? x : 0.01f * x; }

// ---------------- K1: conv_pre  x[4][80][2048] (pad3,k7) -> h[4][2048][256]
__global__ __launch_bounds__(256) void k_conv_pre(const float* __restrict__ x,
    const float* __restrict__ w, const float* __restrict__ bias, float* __restrict__ h)
{
    const int b = blockIdx.y;
    const int t0 = blockIdx.x * 16;
    const int c = threadIdx.x;
    __shared__ float sX[80][22];
    for (int idx = threadIdx.x; idx < 80 * 22; idx += 256) {
        int m = idx / 22, tt = idx - m * 22;
        int ta = t0 - 3 + tt;
        sX[m][tt] = (ta >= 0 && ta < 2048) ? x[(b * 80 + m) * 2048 + ta] : 0.f;
    }
    __syncthreads();
    float acc[16];
    float bv = bias[c];
    #pragma unroll
    for (int i = 0; i < 16; i++) acc[i] = bv;
    const float* wrow = w + c * 560;
    for (int m = 0; m < 80; ++m) {
        float xr[22];
        #pragma unroll
        for (int q = 0; q < 22; q++) xr[q] = sX[m][q];
        #pragma unroll
        for (int k = 0; k < 7; k++) {
            float wv = wrow[m * 7 + k];
            #pragma unroll
            for (int tt = 0; tt < 16; tt++) acc[tt] = fmaf(xr[k + tt], wv, acc[tt]);
        }
    }
    for (int tt = 0; tt < 16; tt++)
        h[(b * 2048 + t0 + tt) * 256 + c] = acc[tt];
}

// ---------------- generic fp32 NT GEMM: C[m,n] = dot(A[m,:K],B[n,:K]) + bias[n]
// PERM: 1 -> x_dbl column interleave (dt | B/C interleaved)
template<int ACT, int PERM>
__global__ __launch_bounds__(256) void k_gemm_nt(const float* __restrict__ A,
    const float* __restrict__ B, const float* __restrict__ bias, float* __restrict__ C,
    int M, int N, int K, int lda, int ldb)
{
    __shared__ float As[16][64];
    __shared__ float Bs[16][64];
    const int bm = blockIdx.y * 64, bn = blockIdx.x * 64;
    const int tid = threadIdx.x;
    const int lm = tid >> 2, lk = (tid & 3) * 4;
    const int tx = tid & 15, ty = tid >> 4;
    float acc[4][4];
    #pragma unroll
    for (int i = 0; i < 4; i++)
        #pragma unroll
        for (int j = 0; j < 4; j++) acc[i][j] = 0.f;
    for (int k0 = 0; k0 < K; k0 += 16) {
        float4 av = make_float4(0.f,0.f,0.f,0.f), bv = make_float4(0.f,0.f,0.f,0.f);
        if (bm + lm < M) av = *(const float4*)(A + (size_t)(bm + lm) * lda + k0 + lk);
        if (bn + lm < N) bv = *(const float4*)(B + (size_t)(bn + lm) * ldb + k0 + lk);
        __syncthreads();
        As[lk + 0][lm] = av.x; As[lk + 1][lm] = av.y; As[lk + 2][lm] = av.z; As[lk + 3][lm] = av.w;
        Bs[lk + 0][lm] = bv.x; Bs[lk + 1][lm] = bv.y; Bs[lk + 2][lm] = bv.z; Bs[lk + 3][lm] = bv.w;
        __syncthreads();
        #pragma unroll
        for (int kk = 0; kk < 16; kk++) {
            float4 a  = *(const float4*)&As[kk][ty * 4];
            float4 b4 = *(const float4*)&Bs[kk][tx * 4];
            acc[0][0] = fmaf(a.x, b4.x, acc[0][0]); acc[0][1] = fmaf(a.x, b4.y, acc[0][1]);
            acc[0][2] = fmaf(a.x, b4.z, acc[0][2]); acc[0][3] = fmaf(a.x, b4.w, acc[0][3]);
            acc[1][0] = fmaf(a.y, b4.x, acc[1][0]); acc[1][1] = fmaf(a.y, b4.y, acc[1][1]);
            acc[1][2] = fmaf(a.y, b4.z, acc[1][2]); acc[1][3] = fmaf(a.y, b4.w, acc[1][3]);
            acc[2][0] = fmaf(a.z, b4.x, acc[2][0]); acc[2][1] = fmaf(a.z, b4.y, acc[2][1]);
            acc[2][2] = fmaf(a.z, b4.z, acc[2][2]); acc[2][3] = fmaf(a.z, b4.w, acc[2][3]);
            acc[3][0] = fmaf(a.w, b4.x, acc[3][0]); acc[3][1] = fmaf(a.w, b4.y, acc[3][1]);
            acc[3][2] = fmaf(a.w, b4.z, acc[3][2]); acc[3][3] = fmaf(a.w, b4.w, acc[3][3]);
        }
    }
    #pragma unroll
    for (int i = 0; i < 4; i++) {
        int m = bm + ty * 4 + i;
        if (m >= M) continue;
        #pragma unroll
        for (int j = 0; j < 4; j++) {
            int n = bn + tx * 4 + j;
            if (n >= N) continue;
            float v = acc[i][j];
            if (bias) v += bias[n];
            int nn = n;
            if (PERM) nn = (n < 16) ? n : (n < 80 ? 16 + 2 * (n - 16) : 17 + 2 * (n - 80));
            C[(size_t)m * N + nn] = v;
        }
    }
}

// ---------------- K3: causal depthwise conv (k=4) + SiLU.  u = xz[:, :512]
__global__ __launch_bounds__(256) void k_dwconv(const float* __restrict__ xz,
    const float* __restrict__ w, const float* __restrict__ bias, float* __restrict__ uc)
{
    int idx = blockIdx.x * 256 + threadIdx.x;     // = i*512 + d
    int i = idx >> 9, d = idx & 511;
    int b = i >> 11, t = i & 2047;
    float4 wv = *(const float4*)(w + d * 4);
    float wk[4] = {wv.x, wv.y, wv.z, wv.w};
    float acc = bias[d];
    const float* base = xz + (size_t)(b * 2048) * 1024 + d;
    #pragma unroll
    for (int k = 0; k < 4; k++) {
        int tt = t - 3 + k;
        if (tt >= 0) acc = fmaf(base[(size_t)tt * 1024], wk[k], acc);
    }
    uc[idx] = siluf_(acc);
}

// ---------------- K4: dt_proj GEMM (M=8192,N=512,K=16) + softplus + pack
// writes packed[(b*512+d)][t] = (delta, delta*u)  (t-contiguous, transposed via LDS)
__global__ __launch_bounds__(256) void k_dtpack(const float* __restrict__ A,
    const float* __restrict__ B, const float* __restrict__ bias,
    const float* __restrict__ uc, float* __restrict__ packed)
{
    __shared__ float As[16][64];
    __shared__ float Bs[16][64];
    __shared__ float2 sT[64][65];
    const int bm = blockIdx.y * 64, bn = blockIdx.x * 64;
    const int tid = threadIdx.x;
    const int lm = tid >> 2, lk = (tid & 3) * 4;
    const int tx = tid & 15, ty = tid >> 4;
    float acc[4][4];
    #pragma unroll
    for (int i = 0; i < 4; i++)
        #pragma unroll
        for (int j = 0; j < 4; j++) acc[i][j] = 0.f;
    {
        float4 av = *(const float4*)(A + (size_t)(bm + lm) * 144 + lk);
        float4 bv = *(const float4*)(B + (size_t)(bn + lm) * 16 + lk);
        As[lk + 0][lm] = av.x; As[lk + 1][lm] = av.y; As[lk + 2][lm] = av.z; As[lk + 3][lm] = av.w;
        Bs[lk + 0][lm] = bv.x; Bs[lk + 1][lm] = bv.y; Bs[lk + 2][lm] = bv.z; Bs[lk + 3][lm] = bv.w;
        __syncthreads();
        #pragma unroll
        for (int kk = 0; kk < 16; kk++) {
            float4 a  = *(const float4*)&As[kk][ty * 4];
            float4 b4 = *(const float4*)&Bs[kk][tx * 4];
            acc[0][0] = fmaf(a.x, b4.x, acc[0][0]); acc[0][1] = fmaf(a.x, b4.y, acc[0][1]);
            acc[0][2] = fmaf(a.x, b4.z, acc[0][2]); acc[0][3] = fmaf(a.x, b4.w, acc[0][3]);
            acc[1][0] = fmaf(a.y, b4.x, acc[1][0]); acc[1][1] = fmaf(a.y, b4.y, acc[1][1]);
            acc[1][2] = fmaf(a.y, b4.z, acc[1][2]); acc[1][3] = fmaf(a.y, b4.w, acc[1][3]);
            acc[2][0] = fmaf(a.z, b4.x, acc[2][0]); acc[2][1] = fmaf(a.z, b4.y, acc[2][1]);
            acc[2][2] = fmaf(a.z, b4.z, acc[2][2]); acc[2][3] = fmaf(a.z, b4.w, acc[2][3]);
            acc[3][0] = fmaf(a.w, b4.x, acc[3][0]); acc[3][1] = fmaf(a.w, b4.y, acc[3][1]);
            acc[3][2] = fmaf(a.w, b4.z, acc[3][2]); acc[3][3] = fmaf(a.w, b4.w, acc[3][3]);
        }
    }
    __syncthreads();
    #pragma unroll
    for (int i = 0; i < 4; i++) {
        int m = bm + ty * 4 + i;
        #pragma unroll
        for (int j = 0; j < 4; j++) {
            int n = bn + tx * 4 + j;
            float v = softplusf_(acc[i][j] + bias[n]);
            float u = uc[(size_t)m * 512 + n];
            sT[tx * 4 + j][ty * 4 + i] = make_float2(v, v * u);
        }
    }
    __syncthreads();
    int b = bm >> 11, tt = bm & 2047;
    int wv = tid >> 6, ln = tid & 63;
    for (int r = wv; r < 64; r += 4)
        *(float2*)(packed + ((size_t)(b * 512 + bn + r) * 2048 + tt + ln) * 2) = sT[r][ln];
}

// ---------------- K5a: scan pass 1 — per-chunk local scan (chunks 0..6), no y
__global__ __launch_bounds__(256) void k_scan1(const float* __restrict__ packed,
    const float* __restrict__ xdbl, const float* __restrict__ A_log,
    float* __restrict__ hloc, float* __restrict__ Pdec)
{
    int lane = threadIdx.x & 63;
    int gid = blockIdx.x * 4 + (threadIdx.x >> 6);  // c*2048 + (b*512+d), c in 0..6
    int c = gid >> 11, bd = gid & 2047;
    int b = bd >> 9, d = bd & 511;
    float Aa = -__expf(A_log[d * 64 + lane]);
    const float* pk  = packed + ((size_t)bd * 2048 + c * 256) * 2;
    const float* pBC = xdbl + (size_t)(b * 2048 + c * 256) * 144 + 16 + 2 * lane;
    float h = 0.f, sumd = 0.f;
    for (int t = 0; t < 256; t += 2) {
        float4 du  = *(const float4*)(pk + t * 2);
        float2 bc0 = *(const float2*)(pBC + (size_t)t * 144);
        float2 bc1 = *(const float2*)(pBC + (size_t)(t + 1) * 144);
        float r0 = __expf(du.x * Aa); h = fmaf(r0, h, du.y * bc0.x);
        float r1 = __expf(du.z * Aa); h = fmaf(r1, h, du.w * bc1.x);
        sumd += du.x + du.z;
    }
    hloc[(size_t)gid * 64 + lane] = h;
    Pdec[(size_t)gid * 64 + lane] = __expf(sumd * Aa);
}

// ---------------- K5b: sequential carry across chunks (tiny)
__global__ __launch_bounds__(256) void k_carry(const float* __restrict__ hloc,
    const float* __restrict__ Pdec, float* __restrict__ hcarry)
{
    int tid = blockIdx.x * 256 + threadIdx.x;   // (b*512+d)*64 + n, 131072 total
    float carry = 0.f;
    hcarry[tid] = 0.f;
    #pragma unroll
    for (int c = 0; c < 7; ++c) {
        carry = fmaf(carry, Pdec[(size_t)c * 131072 + tid], hloc[(size_t)c * 131072 + tid]);
        hcarry[(size_t)(c + 1) * 131072 + tid] = carry;
    }
}

// ---------------- K5c: scan pass 2 — full scan per chunk from carried state
__global__ __launch_bounds__(256) void k_scan2(const float* __restrict__ packed,
    const float* __restrict__ xdbl, const float* __restrict__ A_log,
    const float* __restrict__ hcarry, float* __restrict__ y_scan)
{
    int lane = threadIdx.x & 63;
    int gid = blockIdx.x * 4 + (threadIdx.x >> 6);  // c*2048 + (b*512+d), c in 0..7
    int c = gid >> 11, bd = gid & 2047;
    int b = bd >> 9, d = bd & 511;
    float Aa = -__expf(A_log[d * 64 + lane]);
    const float* pk  = packed + ((size_t)bd * 2048 + c * 256) * 2;
    const float* pBC = xdbl + (size_t)(b * 2048 + c * 256) * 144 + 16 + 2 * lane;
    float* yout = y_scan + (size_t)bd * 2048 + c * 256;
    float h = hcarry[(size_t)gid * 64 + lane];
    float ykeep = 0.f;
    for (int t0 = 0; t0 < 256; t0 += 8) {
        float p[8];
        #pragma unroll
        for (int j = 0; j < 8; j += 2) {
            float4 du  = *(const float4*)(pk + (t0 + j) * 2);
            float2 bc0 = *(const float2*)(pBC + (size_t)(t0 + j) * 144);
            float2 bc1 = *(const float2*)(pBC + (size_t)(t0 + j + 1) * 144);
            float r0 = __expf(du.x * Aa); h = fmaf(r0, h, du.y * bc0.x); p[j] = h * bc0.y;
            float r1 = __expf(du.z * Aa); h = fmaf(r1, h, du.w * bc1.x); p[j + 1] = h * bc1.y;
        }
        #pragma unroll
        for (int off = 32; off >= 1; off >>= 1) {
            #pragma unroll
            for (int j = 0; j < 8; j++) p[j] += __shfl_xor(p[j], off, 64);
        }
        #pragma unroll
        for (int j = 0; j < 8; j++)
            if (lane == ((t0 + j) & 63)) ykeep = p[j];
        if (((t0 + 8) & 63) == 0)
            yout[(t0 & ~63) + lane] = ykeep;
    }
}

// ---------------- K6: g = (y + uc*Dskip) * silu(z), with LDS transpose of y[b,d,t]
__global__ __launch_bounds__(256) void k_combine(const float* __restrict__ y_scan,
    const float* __restrict__ uc, const float* __restrict__ xz,
    const float* __restrict__ Dskip, float* __restrict__ g)
{
    __shared__ float yt[64][65];
    int b = blockIdx.z, d0 = blockIdx.y * 64, t0 = blockIdx.x * 64;
    int tid = threadIdx.x;
    {
        int dd = tid >> 2, q = tid & 3;
        const float* src = y_scan + (size_t)(b * 512 + d0 + dd) * 2048 + t0 + q * 16;
        #pragma unroll
        for (int v = 0; v < 4; v++) {
            float4 f = *(const float4*)(src + v * 4);
            yt[dd][q * 16 + v * 4 + 0] = f.x;
            yt[dd][q * 16 + v * 4 + 1] = f.y;
            yt[dd][q * 16 + v * 4 + 2] = f.z;
            yt[dd][q * 16 + v * 4 + 3] = f.w;
        }
    }
    __syncthreads();
    int dl = tid & 63, tg = tid >> 6;
    int d = d0 + dl;
    float ds = Dskip[d];
    for (int j = 0; j < 16; j++) {
        int tt = tg * 16 + j;
        int i = b * 2048 + t0 + tt;
        float y = yt[dl][tt];
        float u = uc[(size_t)i * 512 + d];
        float z = xz[(size_t)i * 1024 + 512 + d];
        g[(size_t)i * 512 + d] = (y + u * ds) * siluf_(z);
    }
}

// ---------------- K9: transpose conv_post_w [18][256][7] -> wT [7][18][256]
__global__ void k_transpose_wpost(const float* __restrict__ w, float* __restrict__ wT)
{
    int idx = blockIdx.x * 256 + threadIdx.x;
    if (idx >= 18 * 256 * 7) return;
    int o = idx / 1792, rem = idx - o * 1792;
    int c = rem / 7, k = rem - c * 7;
    wT[k * 4608 + o * 256 + c] = w[idx];
}

// ---------------- K7: lrelu + conv_post (k=7,pad3) + exp/sin epilogue
__global__ __launch_bounds__(256) void k_conv_post(const float* __restrict__ mid,
    const float* __restrict__ wT, const float* __restrict__ bias, float* __restrict__ out)
{
    __shared__ float sX[256][40];
    __shared__ float wk[24 * 256];
    int b = blockIdx.y, t0 = blockIdx.x * 32;
    int tid = threadIdx.x;
    for (int r = 0; r < 38; ++r) {
        int ta = t0 - 3 + r;
        float v = 0.f;
        if (ta >= 0 && ta < 2048) v = lreluf_(mid[(size_t)(b * 2048 + ta) * 256 + tid]);
        sX[tid][r] = v;
    }
    int t = tid & 31, og = tid >> 5;    // 8 groups, o = og + 8j
    float acc[3];
    #pragma unroll
    for (int j = 0; j < 3; j++) { int o = og + 8 * j; acc[j] = (o < 18) ? bias[o] : 0.f; }
    for (int k = 0; k < 7; ++k) {
        __syncthreads();
        for (int idx = tid; idx < 24 * 256; idx += 256)
            wk[idx] = (idx < 18 * 256) ? wT[k * 4608 + idx] : 0.f;
        __syncthreads();
        for (int c = 0; c < 256; ++c) {
            float xv = sX[c][t + k];
            acc[0] = fmaf(xv, wk[og * 256 + c], acc[0]);
            acc[1] = fmaf(xv, wk[(og + 8) * 256 + c], acc[1]);
            acc[2] = fmaf(xv, wk[(og + 16) * 256 + c], acc[2]);
        }
    }
    int ta = t0 + t;
    #pragma unroll
    for (int j = 0; j < 3; j++) {
        int o = og + 8 * j;
        if (o >= 18) continue;
        float v = acc[j];
        if (o < 9) out[(size_t)(b * 9 + o) * 2048 + ta] = __expf(v);
        else       out[73728 + (size_t)(b * 9 + (o - 9)) * 2048 + ta] = __sinf(v);
    }
}

extern "C" void kernel_launch(void* const* d_in, const int* in_sizes, int n_in,
                              void* d_out, int out_size, void* d_ws, size_t ws_size,
                              hipStream_t stream)
{
    const float* x         = (const float*)d_in[0];
    const float* pre_w     = (const float*)d_in[1];
    const float* pre_b     = (const float*)d_in[2];
    const float* inproj_w  = (const float*)d_in[3];
    const float* dw_w      = (const float*)d_in[4];
    const float* dw_b      = (const float*)d_in[5];
    const float* xproj_w   = (const float*)d_in[6];
    const float* dt_w      = (const float*)d_in[7];
    const float* dt_b      = (const float*)d_in[8];
    const float* A_log     = (const float*)d_in[9];
    const float* Dskip     = (const float*)d_in[10];
    const float* outproj_w = (const float*)d_in[11];
    const float* post_w    = (const float*)d_in[12];
    const float* post_b    = (const float*)d_in[13];
    float* out = (float*)d_out;
    float* W = (float*)d_ws;

    float* h_pre   = W;                 //  2,097,152 floats (reused as out_mid)
    float* xz      = W + 2097152;       //  8,388,608
    float* uc      = W + 10485760;      //  4,194,304
    float* x_dbl   = W + 14680064;      //  1,179,648 (cols: dt 0..15, BC interleaved 16..143)
    float* packed  = W + 15859712;      //  8,388,608  (delta, delta*u) per (b,d), t-contig
    float* y_scan  = W + 24248320;      //  4,194,304
    float* g       = W + 28442624;      //  4,194,304 (hloc/Pdec/hcarry live here pre-combine)
    float* wTpost  = W + 32636928;      //  32,256
    float* out_mid = h_pre;
    float* hloc    = g;                 //  917,504 (7*131072)
    float* Pdec    = g + 917504;        //  917,504
    float* hcarry  = g + 1835008;       //  1,048,576 (8*131072)

    k_conv_pre<<<dim3(128, 4), 256, 0, stream>>>(x, pre_w, pre_b, h_pre);
    k_gemm_nt<0,0><<<dim3(16, 128), 256, 0, stream>>>(h_pre, inproj_w, nullptr, xz,
                                                      8192, 1024, 256, 256, 256);
    k_dwconv<<<16384, 256, 0, stream>>>(xz, dw_w, dw_b, uc);
    k_gemm_nt<0,1><<<dim3(3, 128), 256, 0, stream>>>(uc, xproj_w, nullptr, x_dbl,
                                                     8192, 144, 512, 512, 512);
    k_dtpack<<<dim3(8, 128), 256, 0, stream>>>(x_dbl, dt_w, dt_b, uc, packed);
    k_scan1<<<3584, 256, 0, stream>>>(packed, x_dbl, A_log, hloc, Pdec);
    k_carry<<<512, 256, 0, stream>>>(hloc, Pdec, hcarry);
    k_scan2<<<4096, 256, 0, stream>>>(packed, x_dbl, A_log, hcarry, y_scan);
    k_combine<<<dim3(32, 8, 4), 256, 0, stream>>>(y_scan, uc, xz, Dskip, g);
    k_gemm_nt<0,0><<<dim3(4, 128), 256, 0, stream>>>(g, outproj_w, nullptr, out_mid,
                                                     8192, 256, 512, 512, 512);
    k_transpose_wpost<<<126, 256, 0, stream>>>(post_w, wTpost);
    k_conv_post<<<dim3(64, 4), 256, 0, stream>>>(out_mid, wTpost, post_b, out);
}

// Round 3
// 666.846 us; speedup vs baseline: 1.2131x; 1.2131x over previous
//
#include <hip/hip_runtime.h>
#include <cstdint>

#define DEV __device__ __forceinline__

DEV float sigmoidf_(float x){ return 1.f / (1.f + __expf(-x)); }
DEV float siluf_(float x){ return x * sigmoidf_(x); }
DEV float softplusf_(float x){ return x > 20.f ? x : log1pf(__expf(x)); }
DEV float lreluf_(float x){ return x >= 0.f ? x : 0.01f * x; }

// ---------------- K1: conv_pre  x[4][80][2048] (pad3,k7) -> h[4][2048][256]
__global__ __launch_bounds__(256) void k_conv_pre(const float* __restrict__ x,
    const float* __restrict__ w, const float* __restrict__ bias, float* __restrict__ h)
{
    const int b = blockIdx.y;
    const int t0 = blockIdx.x * 16;
    const int c = threadIdx.x;
    __shared__ float sX[80][22];
    for (int idx = threadIdx.x; idx < 80 * 22; idx += 256) {
        int m = idx / 22, tt = idx - m * 22;
        int ta = t0 - 3 + tt;
        sX[m][tt] = (ta >= 0 && ta < 2048) ? x[(b * 80 + m) * 2048 + ta] : 0.f;
    }
    __syncthreads();
    float acc[16];
    float bv = bias[c];
    #pragma unroll
    for (int i = 0; i < 16; i++) acc[i] = bv;
    const float* wrow = w + c * 560;
    for (int m = 0; m < 80; ++m) {
        float xr[22];
        #pragma unroll
        for (int q = 0; q < 22; q++) xr[q] = sX[m][q];
        #pragma unroll
        for (int k = 0; k < 7; k++) {
            float wv = wrow[m * 7 + k];
            #pragma unroll
            for (int tt = 0; tt < 16; tt++) acc[tt] = fmaf(xr[k + tt], wv, acc[tt]);
        }
    }
    for (int tt = 0; tt < 16; tt++)
        h[(b * 2048 + t0 + tt) * 256 + c] = acc[tt];
}

// ---------------- generic fp32 NT GEMM: C[m,n] = act(dot(A[m,:K],B[n,:K]) + bias[n])
// ACT: 0 none, 1 softplus.  PERM: 1 -> x_dbl column interleave (dt | B/C interleaved)
template<int ACT, int PERM>
__global__ __launch_bounds__(256) void k_gemm_nt(const float* __restrict__ A,
    const float* __restrict__ B, const float* __restrict__ bias, float* __restrict__ C,
    int M, int N, int K, int lda, int ldb)
{
    __shared__ float As[16][64];
    __shared__ float Bs[16][64];
    const int bm = blockIdx.y * 64, bn = blockIdx.x * 64;
    const int tid = threadIdx.x;
    const int lm = tid >> 2, lk = (tid & 3) * 4;
    const int tx = tid & 15, ty = tid >> 4;
    float acc[4][4];
    #pragma unroll
    for (int i = 0; i < 4; i++)
        #pragma unroll
        for (int j = 0; j < 4; j++) acc[i][j] = 0.f;
    for (int k0 = 0; k0 < K; k0 += 16) {
        float4 av = make_float4(0.f,0.f,0.f,0.f), bv = make_float4(0.f,0.f,0.f,0.f);
        if (bm + lm < M) av = *(const float4*)(A + (size_t)(bm + lm) * lda + k0 + lk);
        if (bn + lm < N) bv = *(const float4*)(B + (size_t)(bn + lm) * ldb + k0 + lk);
        __syncthreads();
        As[lk + 0][lm] = av.x; As[lk + 1][lm] = av.y; As[lk + 2][lm] = av.z; As[lk + 3][lm] = av.w;
        Bs[lk + 0][lm] = bv.x; Bs[lk + 1][lm] = bv.y; Bs[lk + 2][lm] = bv.z; Bs[lk + 3][lm] = bv.w;
        __syncthreads();
        #pragma unroll
        for (int kk = 0; kk < 16; kk++) {
            float4 a  = *(const float4*)&As[kk][ty * 4];
            float4 b4 = *(const float4*)&Bs[kk][tx * 4];
            acc[0][0] = fmaf(a.x, b4.x, acc[0][0]); acc[0][1] = fmaf(a.x, b4.y, acc[0][1]);
            acc[0][2] = fmaf(a.x, b4.z, acc[0][2]); acc[0][3] = fmaf(a.x, b4.w, acc[0][3]);
            acc[1][0] = fmaf(a.y, b4.x, acc[1][0]); acc[1][1] = fmaf(a.y, b4.y, acc[1][1]);
            acc[1][2] = fmaf(a.y, b4.z, acc[1][2]); acc[1][3] = fmaf(a.y, b4.w, acc[1][3]);
            acc[2][0] = fmaf(a.z, b4.x, acc[2][0]); acc[2][1] = fmaf(a.z, b4.y, acc[2][1]);
            acc[2][2] = fmaf(a.z, b4.z, acc[2][2]); acc[2][3] = fmaf(a.z, b4.w, acc[2][3]);
            acc[3][0] = fmaf(a.w, b4.x, acc[3][0]); acc[3][1] = fmaf(a.w, b4.y, acc[3][1]);
            acc[3][2] = fmaf(a.w, b4.z, acc[3][2]); acc[3][3] = fmaf(a.w, b4.w, acc[3][3]);
        }
    }
    #pragma unroll
    for (int i = 0; i < 4; i++) {
        int m = bm + ty * 4 + i;
        if (m >= M) continue;
        #pragma unroll
        for (int j = 0; j < 4; j++) {
            int n = bn + tx * 4 + j;
            if (n >= N) continue;
            float v = acc[i][j];
            if (bias) v += bias[n];
            if (ACT == 1) v = softplusf_(v);
            int nn = n;
            if (PERM) nn = (n < 16) ? n : (n < 80 ? 16 + 2 * (n - 16) : 17 + 2 * (n - 80));
            C[(size_t)m * N + nn] = v;
        }
    }
}

// ---------------- K3: causal depthwise conv (k=4) + SiLU.  u = xz[:, :512]
__global__ __launch_bounds__(256) void k_dwconv(const float* __restrict__ xz,
    const float* __restrict__ w, const float* __restrict__ bias, float* __restrict__ uc)
{
    int idx = blockIdx.x * 256 + threadIdx.x;     // = i*512 + d
    int i = idx >> 9, d = idx & 511;
    int b = i >> 11, t = i & 2047;
    float4 wv = *(const float4*)(w + d * 4);
    float wk[4] = {wv.x, wv.y, wv.z, wv.w};
    float acc = bias[d];
    const float* base = xz + (size_t)(b * 2048) * 1024 + d;
    #pragma unroll
    for (int k = 0; k < 4; k++) {
        int tt = t - 3 + k;
        if (tt >= 0) acc = fmaf(base[(size_t)tt * 1024], wk[k], acc);
    }
    uc[idx] = siluf_(acc);
}

// ---------------- K5a: scan pass 1 — per-chunk local scan (32 chunks of 64 t,
// chunks 0..30), lane = n, no y-reduction. Outputs hloc + chunk decay P.
__global__ __launch_bounds__(256) void k_scan1(const float* __restrict__ delta,
    const float* __restrict__ uc, const float* __restrict__ xdbl,
    const float* __restrict__ A_log, float* __restrict__ hloc, float* __restrict__ Pdec)
{
    int lane = threadIdx.x & 63;
    int wv = __builtin_amdgcn_readfirstlane((int)(threadIdx.x >> 6));
    int gid = blockIdx.x * 4 + wv;          // c*2048 + (b*512+d), c in 0..30
    int c = gid >> 11, bd = gid & 2047;
    int b = bd >> 9, d = bd & 511;
    float Aa = -__expf(A_log[d * 64 + lane]);
    const float* pBC = xdbl + (size_t)(b * 2048 + c * 64) * 144 + 16 + 2 * lane;
    const float* pD  = delta + (size_t)(b * 2048 + c * 64) * 512 + d;
    const float* pU  = uc    + (size_t)(b * 2048 + c * 64) * 512 + d;
    float h = 0.f, sumd = 0.f;
    #pragma unroll 4
    for (int t = 0; t < 64; ++t) {
        float dl  = pD[(size_t)t * 512];
        float uu  = pU[(size_t)t * 512];
        float2 bc = *(const float2*)(pBC + (size_t)t * 144);
        float r = __expf(dl * Aa);
        h = fmaf(r, h, dl * uu * bc.x);
        sumd += dl;
    }
    hloc[(size_t)gid * 64 + lane] = h;
    Pdec[(size_t)gid * 64 + lane] = __expf(sumd * Aa);
}

// ---------------- K5b: sequential carry across 31 chunks, in-place into hloc.
// After this, hloc[c] holds the inclusive carry through chunk c (= h-init for c+1).
__global__ __launch_bounds__(256) void k_carry(float* __restrict__ hloc,
    const float* __restrict__ Pdec)
{
    int tid = blockIdx.x * 256 + threadIdx.x;   // (b*512+d)*64 + n, 131072 total
    float carry = hloc[tid];                    // c=0 inclusive carry = hloc[0]
    for (int cc = 1; cc < 31; ++cc) {
        size_t o = (size_t)cc * 131072 + tid;
        carry = fmaf(carry, Pdec[o], hloc[o]);
        hloc[o] = carry;
    }
}

// ---------------- K5c: scan pass 2, lane = d (64 channels/wave, all 64 states in
// registers). No cross-lane reduction. Fused combine epilogue:
// g = (y + u*Dskip) * silu(z), written (b,t,d)-major.
__global__ __launch_bounds__(256, 1) void k_scan2f(const float* __restrict__ delta,
    const float* __restrict__ uc, const float* __restrict__ xz,
    const float* __restrict__ xdbl, const float* __restrict__ A_log,
    const float* __restrict__ hcar, const float* __restrict__ Dskip,
    float* __restrict__ g)
{
    __shared__ float sBC[64 * 128];             // 64 t x (B,C interleaved 128 floats)
    const int tid = threadIdx.x;
    const int c = blockIdx.x, b = blockIdx.z;
    const int d = blockIdx.y * 256 + (tid & 255);   // lane = d within wave's 64-group
    // stage B/C tile for this chunk (uniform across lanes at read time)
    for (int idx = tid; idx < 2048; idx += 256) {
        int r = idx >> 5, q = idx & 31;
        *(float4*)&sBC[r * 128 + q * 4] =
            *(const float4*)(xdbl + (size_t)(b * 2048 + c * 64 + r) * 144 + 16 + q * 4);
    }
    float A[64], h[64];
    #pragma unroll
    for (int k = 0; k < 16; ++k) {
        float4 al = *(const float4*)(A_log + (size_t)d * 64 + k * 4);
        A[4 * k + 0] = -__expf(al.x); A[4 * k + 1] = -__expf(al.y);
        A[4 * k + 2] = -__expf(al.z); A[4 * k + 3] = -__expf(al.w);
    }
    if (c == 0) {
        #pragma unroll
        for (int n = 0; n < 64; ++n) h[n] = 0.f;
    } else {
        const float* hp = hcar + ((size_t)(c - 1) * 2048 + b * 512 + d) * 64;
        #pragma unroll
        for (int k = 0; k < 16; ++k) {
            float4 hv = *(const float4*)(hp + k * 4);
            h[4 * k + 0] = hv.x; h[4 * k + 1] = hv.y;
            h[4 * k + 2] = hv.z; h[4 * k + 3] = hv.w;
        }
    }
    __syncthreads();
    const float dsk = Dskip[d];
    for (int t = 0; t < 64; ++t) {
        size_t R = (size_t)(b * 2048 + c * 64 + t);
        float dl = delta[R * 512 + d];
        float u  = uc[R * 512 + d];
        float z  = xz[R * 1024 + 512 + d];
        float du = dl * u;
        const float* bct = &sBC[t * 128];
        float y0 = 0.f, y1 = 0.f;
        #pragma unroll
        for (int n = 0; n < 64; n += 2) {
            float4 bc = *(const float4*)(bct + 2 * n);   // B_n,C_n,B_{n+1},C_{n+1}
            float e0 = __expf(dl * A[n]);
            h[n] = fmaf(e0, h[n], du * bc.x);
            y0 = fmaf(h[n], bc.y, y0);
            float e1 = __expf(dl * A[n + 1]);
            h[n + 1] = fmaf(e1, h[n + 1], du * bc.z);
            y1 = fmaf(h[n + 1], bc.w, y1);
        }
        float y = y0 + y1 + u * dsk;
        g[R * 512 + d] = y * siluf_(z);
    }
}

// ---------------- K9: transpose conv_post_w [18][256][7] -> wT [7][18][256]
__global__ void k_transpose_wpost(const float* __restrict__ w, float* __restrict__ wT)
{
    int idx = blockIdx.x * 256 + threadIdx.x;
    if (idx >= 18 * 256 * 7) return;
    int o = idx / 1792, rem = idx - o * 1792;
    int c = rem / 7, k = rem - c * 7;
    wT[k * 4608 + o * 256 + c] = w[idx];
}

// ---------------- K7: lrelu + conv_post (k=7,pad3) + exp/sin epilogue
__global__ __launch_bounds__(256) void k_conv_post(const float* __restrict__ mid,
    const float* __restrict__ wT, const float* __restrict__ bias, float* __restrict__ out)
{
    __shared__ float sX[256][40];
    __shared__ float wk[24 * 256];
    int b = blockIdx.y, t0 = blockIdx.x * 32;
    int tid = threadIdx.x;
    for (int r = 0; r < 38; ++r) {
        int ta = t0 - 3 + r;
        float v = 0.f;
        if (ta >= 0 && ta < 2048) v = lreluf_(mid[(size_t)(b * 2048 + ta) * 256 + tid]);
        sX[tid][r] = v;
    }
    int t = tid & 31, og = tid >> 5;    // 8 groups, o = og + 8j
    float acc[3];
    #pragma unroll
    for (int j = 0; j < 3; j++) { int o = og + 8 * j; acc[j] = (o < 18) ? bias[o] : 0.f; }
    for (int k = 0; k < 7; ++k) {
        __syncthreads();
        for (int idx = tid; idx < 24 * 256; idx += 256)
            wk[idx] = (idx < 18 * 256) ? wT[k * 4608 + idx] : 0.f;
        __syncthreads();
        for (int c = 0; c < 256; ++c) {
            float xv = sX[c][t + k];
            acc[0] = fmaf(xv, wk[og * 256 + c], acc[0]);
            acc[1] = fmaf(xv, wk[(og + 8) * 256 + c], acc[1]);
            acc[2] = fmaf(xv, wk[(og + 16) * 256 + c], acc[2]);
        }
    }
    int ta = t0 + t;
    #pragma unroll
    for (int j = 0; j < 3; j++) {
        int o = og + 8 * j;
        if (o >= 18) continue;
        float v = acc[j];
        if (o < 9) out[(size_t)(b * 9 + o) * 2048 + ta] = __expf(v);
        else       out[73728 + (size_t)(b * 9 + (o - 9)) * 2048 + ta] = __sinf(v);
    }
}

extern "C" void kernel_launch(void* const* d_in, const int* in_sizes, int n_in,
                              void* d_out, int out_size, void* d_ws, size_t ws_size,
                              hipStream_t stream)
{
    const float* x         = (const float*)d_in[0];
    const float* pre_w     = (const float*)d_in[1];
    const float* pre_b     = (const float*)d_in[2];
    const float* inproj_w  = (const float*)d_in[3];
    const float* dw_w      = (const float*)d_in[4];
    const float* dw_b      = (const float*)d_in[5];
    const float* xproj_w   = (const float*)d_in[6];
    const float* dt_w      = (const float*)d_in[7];
    const float* dt_b      = (const float*)d_in[8];
    const float* A_log     = (const float*)d_in[9];
    const float* Dskip     = (const float*)d_in[10];
    const float* outproj_w = (const float*)d_in[11];
    const float* post_w    = (const float*)d_in[12];
    const float* post_b    = (const float*)d_in[13];
    float* out = (float*)d_out;
    float* W = (float*)d_ws;

    float* h_pre   = W;                 //  2,097,152 floats (reused as out_mid)
    float* xz      = W + 2097152;       //  8,388,608
    float* uc      = W + 10485760;      //  4,194,304
    float* x_dbl   = W + 14680064;      //  1,179,648 (cols: dt 0..15, BC interleaved 16..143)
    float* delta   = W + 15859712;      //  4,194,304  (b,t,d)-major
    float* hloc    = W + 20054016;      //  4,063,232 (31*131072; becomes carry in-place)
    float* Pdec    = W + 24117248;      //  4,063,232
    float* g       = W + 28180480;      //  4,194,304
    float* wTpost  = W + 32374784;      //  32,256   (total 32,407,040 floats)
    float* out_mid = h_pre;

    k_conv_pre<<<dim3(128, 4), 256, 0, stream>>>(x, pre_w, pre_b, h_pre);
    k_gemm_nt<0,0><<<dim3(16, 128), 256, 0, stream>>>(h_pre, inproj_w, nullptr, xz,
                                                      8192, 1024, 256, 256, 256);
    k_dwconv<<<16384, 256, 0, stream>>>(xz, dw_w, dw_b, uc);
    k_gemm_nt<0,1><<<dim3(3, 128), 256, 0, stream>>>(uc, xproj_w, nullptr, x_dbl,
                                                     8192, 144, 512, 512, 512);
    k_gemm_nt<1,0><<<dim3(8, 128), 256, 0, stream>>>(x_dbl, dt_w, dt_b, delta,
                                                     8192, 512, 16, 144, 16);
    k_scan1<<<15872, 256, 0, stream>>>(delta, uc, x_dbl, A_log, hloc, Pdec);
    k_carry<<<512, 256, 0, stream>>>(hloc, Pdec);
    k_scan2f<<<dim3(32, 2, 4), 256, 0, stream>>>(delta, uc, xz, x_dbl, A_log,
                                                 hloc, Dskip, g);
    k_gemm_nt<0,0><<<dim3(4, 128), 256, 0, stream>>>(g, outproj_w, nullptr, out_mid,
                                                     8192, 256, 512, 512, 512);
    k_transpose_wpost<<<126, 256, 0, stream>>>(post_w, wTpost);
    k_conv_post<<<dim3(64, 4), 256, 0, stream>>>(out_mid, wTpost, post_b, out);
}

// Round 4
// 578.297 us; speedup vs baseline: 1.3988x; 1.1531x over previous
//
#include <hip/hip_runtime.h>
#include <cstdint>

#define DEV __device__ __forceinline__

DEV float sigmoidf_(float x){ return 1.f / (1.f + __expf(-x)); }
DEV float siluf_(float x){ return x * sigmoidf_(x); }
DEV float softplusf_(float x){ return x > 20.f ? x : log1pf(__expf(x)); }
DEV float lreluf_(float x){ return x >= 0.f ? x : 0.01f * x; }

// ---------------- K1: conv_pre  x[4][80][2048] (pad3,k7) -> h[4][2048][256]
__global__ __launch_bounds__(256) void k_conv_pre(const float* __restrict__ x,
    const float* __restrict__ w, const float* __restrict__ bias, float* __restrict__ h)
{
    const int b = blockIdx.y;
    const int t0 = blockIdx.x * 16;
    const int c = threadIdx.x;
    __shared__ float sX[80][22];
    for (int idx = threadIdx.x; idx < 80 * 22; idx += 256) {
        int m = idx / 22, tt = idx - m * 22;
        int ta = t0 - 3 + tt;
        sX[m][tt] = (ta >= 0 && ta < 2048) ? x[(b * 80 + m) * 2048 + ta] : 0.f;
    }
    __syncthreads();
    float acc[16];
    float bv = bias[c];
    #pragma unroll
    for (int i = 0; i < 16; i++) acc[i] = bv;
    const float* wrow = w + c * 560;
    for (int m = 0; m < 80; ++m) {
        float xr[22];
        #pragma unroll
        for (int q = 0; q < 22; q++) xr[q] = sX[m][q];
        #pragma unroll
        for (int k = 0; k < 7; k++) {
            float wv = wrow[m * 7 + k];
            #pragma unroll
            for (int tt = 0; tt < 16; tt++) acc[tt] = fmaf(xr[k + tt], wv, acc[tt]);
        }
    }
    for (int tt = 0; tt < 16; tt++)
        h[(b * 2048 + t0 + tt) * 256 + c] = acc[tt];
}

// ---------------- generic fp32 NT GEMM: C[m,n] = act(dot(A[m,:K],B[n,:K]) + bias[n])
// ACT: 0 none, 1 softplus.  PERM: 1 -> x_dbl column interleave (dt | B/C interleaved)
template<int ACT, int PERM>
__global__ __launch_bounds__(256) void k_gemm_nt(const float* __restrict__ A,
    const float* __restrict__ B, const float* __restrict__ bias, float* __restrict__ C,
    int M, int N, int K, int lda, int ldb)
{
    __shared__ float As[16][64];
    __shared__ float Bs[16][64];
    const int bm = blockIdx.y * 64, bn = blockIdx.x * 64;
    const int tid = threadIdx.x;
    const int lm = tid >> 2, lk = (tid & 3) * 4;
    const int tx = tid & 15, ty = tid >> 4;
    float acc[4][4];
    #pragma unroll
    for (int i = 0; i < 4; i++)
        #pragma unroll
        for (int j = 0; j < 4; j++) acc[i][j] = 0.f;
    for (int k0 = 0; k0 < K; k0 += 16) {
        float4 av = make_float4(0.f,0.f,0.f,0.f), bv = make_float4(0.f,0.f,0.f,0.f);
        if (bm + lm < M) av = *(const float4*)(A + (size_t)(bm + lm) * lda + k0 + lk);
        if (bn + lm < N) bv = *(const float4*)(B + (size_t)(bn + lm) * ldb + k0 + lk);
        __syncthreads();
        As[lk + 0][lm] = av.x; As[lk + 1][lm] = av.y; As[lk + 2][lm] = av.z; As[lk + 3][lm] = av.w;
        Bs[lk + 0][lm] = bv.x; Bs[lk + 1][lm] = bv.y; Bs[lk + 2][lm] = bv.z; Bs[lk + 3][lm] = bv.w;
        __syncthreads();
        #pragma unroll
        for (int kk = 0; kk < 16; kk++) {
            float4 a  = *(const float4*)&As[kk][ty * 4];
            float4 b4 = *(const float4*)&Bs[kk][tx * 4];
            acc[0][0] = fmaf(a.x, b4.x, acc[0][0]); acc[0][1] = fmaf(a.x, b4.y, acc[0][1]);
            acc[0][2] = fmaf(a.x, b4.z, acc[0][2]); acc[0][3] = fmaf(a.x, b4.w, acc[0][3]);
            acc[1][0] = fmaf(a.y, b4.x, acc[1][0]); acc[1][1] = fmaf(a.y, b4.y, acc[1][1]);
            acc[1][2] = fmaf(a.y, b4.z, acc[1][2]); acc[1][3] = fmaf(a.y, b4.w, acc[1][3]);
            acc[2][0] = fmaf(a.z, b4.x, acc[2][0]); acc[2][1] = fmaf(a.z, b4.y, acc[2][1]);
            acc[2][2] = fmaf(a.z, b4.z, acc[2][2]); acc[2][3] = fmaf(a.z, b4.w, acc[2][3]);
            acc[3][0] = fmaf(a.w, b4.x, acc[3][0]); acc[3][1] = fmaf(a.w, b4.y, acc[3][1]);
            acc[3][2] = fmaf(a.w, b4.z, acc[3][2]); acc[3][3] = fmaf(a.w, b4.w, acc[3][3]);
        }
    }
    #pragma unroll
    for (int i = 0; i < 4; i++) {
        int m = bm + ty * 4 + i;
        if (m >= M) continue;
        #pragma unroll
        for (int j = 0; j < 4; j++) {
            int n = bn + tx * 4 + j;
            if (n >= N) continue;
            float v = acc[i][j];
            if (bias) v += bias[n];
            if (ACT == 1) v = softplusf_(v);
            int nn = n;
            if (PERM) nn = (n < 16) ? n : (n < 80 ? 16 + 2 * (n - 16) : 17 + 2 * (n - 80));
            C[(size_t)m * N + nn] = v;
        }
    }
}

// ---------------- K3: causal depthwise conv (k=4) + SiLU.  u = xz[:, :512]
__global__ __launch_bounds__(256) void k_dwconv(const float* __restrict__ xz,
    const float* __restrict__ w, const float* __restrict__ bias, float* __restrict__ uc)
{
    int idx = blockIdx.x * 256 + threadIdx.x;     // = i*512 + d
    int i = idx >> 9, d = idx & 511;
    int b = i >> 11, t = i & 2047;
    float4 wv = *(const float4*)(w + d * 4);
    float wk[4] = {wv.x, wv.y, wv.z, wv.w};
    float acc = bias[d];
    const float* base = xz + (size_t)(b * 2048) * 1024 + d;
    #pragma unroll
    for (int k = 0; k < 4; k++) {
        int tt = t - 3 + k;
        if (tt >= 0) acc = fmaf(base[(size_t)tt * 1024], wk[k], acc);
    }
    uc[idx] = siluf_(acc);
}

// ---------------- K5a: scan pass 1 — per-chunk local scan (32 chunks of 64 t,
// chunks 0..30). lane = d, 64 states in registers, B tile staged in LDS.
// Coalesced delta/uc reads. Outputs hloc + chunk decay P ([c][bd][n] layout).
__global__ __launch_bounds__(256, 1) void k_scan1(const float* __restrict__ delta,
    const float* __restrict__ uc, const float* __restrict__ xdbl,
    const float* __restrict__ A_log, float* __restrict__ hloc, float* __restrict__ Pdec)
{
    __shared__ float sBC[64 * 128];             // 64 t x (B,C interleaved 128 floats)
    const int tid = threadIdx.x;
    const int c = blockIdx.x, b = blockIdx.z;
    const int d = blockIdx.y * 256 + tid;
    for (int idx = tid; idx < 2048; idx += 256) {
        int r = idx >> 5, q = idx & 31;
        *(float4*)&sBC[r * 128 + q * 4] =
            *(const float4*)(xdbl + (size_t)(b * 2048 + c * 64 + r) * 144 + 16 + q * 4);
    }
    float A[64], h[64];
    #pragma unroll
    for (int k = 0; k < 16; ++k) {
        float4 al = *(const float4*)(A_log + (size_t)d * 64 + k * 4);
        A[4 * k + 0] = -__expf(al.x); A[4 * k + 1] = -__expf(al.y);
        A[4 * k + 2] = -__expf(al.z); A[4 * k + 3] = -__expf(al.w);
    }
    #pragma unroll
    for (int n = 0; n < 64; ++n) h[n] = 0.f;
    __syncthreads();
    const float* pD = delta + (size_t)(b * 2048 + c * 64) * 512 + d;
    const float* pU = uc    + (size_t)(b * 2048 + c * 64) * 512 + d;
    float sumd = 0.f;
    for (int t = 0; t < 64; ++t) {
        float dl = pD[(size_t)t * 512];
        float u  = pU[(size_t)t * 512];
        float du = dl * u;
        sumd += dl;
        const float* bct = &sBC[t * 128];
        #pragma unroll
        for (int n = 0; n < 64; n += 2) {
            float4 bc = *(const float4*)(bct + 2 * n);   // B_n,C_n,B_{n+1},C_{n+1}
            h[n]     = fmaf(__expf(dl * A[n]),     h[n],     du * bc.x);
            h[n + 1] = fmaf(__expf(dl * A[n + 1]), h[n + 1], du * bc.z);
        }
    }
    float* hp = hloc + ((size_t)c * 2048 + b * 512 + d) * 64;
    float* pp = Pdec + ((size_t)c * 2048 + b * 512 + d) * 64;
    #pragma unroll
    for (int n = 0; n < 64; n += 4) {
        *(float4*)(hp + n) = make_float4(h[n], h[n + 1], h[n + 2], h[n + 3]);
        *(float4*)(pp + n) = make_float4(__expf(sumd * A[n]),     __expf(sumd * A[n + 1]),
                                         __expf(sumd * A[n + 2]), __expf(sumd * A[n + 3]));
    }
}

// ---------------- K5b: sequential carry across 31 chunks, in-place into hloc.
// After this, hloc[c] holds the inclusive carry through chunk c (= h-init for c+1).
__global__ __launch_bounds__(256) void k_carry(float* __restrict__ hloc,
    const float* __restrict__ Pdec)
{
    int tid = blockIdx.x * 256 + threadIdx.x;   // (b*512+d)*64 + n, 131072 total
    float carry = hloc[tid];                    // c=0 inclusive carry = hloc[0]
    for (int cc = 1; cc < 31; ++cc) {
        size_t o = (size_t)cc * 131072 + tid;
        carry = fmaf(carry, Pdec[o], hloc[o]);
        hloc[o] = carry;
    }
}

// ---------------- K5c: scan pass 2, lane = d (64 channels/wave, all 64 states in
// registers). No cross-lane reduction. Fused combine epilogue:
// g = (y + u*Dskip) * silu(z), written (b,t,d)-major.
__global__ __launch_bounds__(256, 1) void k_scan2f(const float* __restrict__ delta,
    const float* __restrict__ uc, const float* __restrict__ xz,
    const float* __restrict__ xdbl, const float* __restrict__ A_log,
    const float* __restrict__ hcar, const float* __restrict__ Dskip,
    float* __restrict__ g)
{
    __shared__ float sBC[64 * 128];             // 64 t x (B,C interleaved 128 floats)
    const int tid = threadIdx.x;
    const int c = blockIdx.x, b = blockIdx.z;
    const int d = blockIdx.y * 256 + (tid & 255);   // lane = d within wave's 64-group
    // stage B/C tile for this chunk (uniform across lanes at read time)
    for (int idx = tid; idx < 2048; idx += 256) {
        int r = idx >> 5, q = idx & 31;
        *(float4*)&sBC[r * 128 + q * 4] =
            *(const float4*)(xdbl + (size_t)(b * 2048 + c * 64 + r) * 144 + 16 + q * 4);
    }
    float A[64], h[64];
    #pragma unroll
    for (int k = 0; k < 16; ++k) {
        float4 al = *(const float4*)(A_log + (size_t)d * 64 + k * 4);
        A[4 * k + 0] = -__expf(al.x); A[4 * k + 1] = -__expf(al.y);
        A[4 * k + 2] = -__expf(al.z); A[4 * k + 3] = -__expf(al.w);
    }
    if (c == 0) {
        #pragma unroll
        for (int n = 0; n < 64; ++n) h[n] = 0.f;
    } else {
        const float* hp = hcar + ((size_t)(c - 1) * 2048 + b * 512 + d) * 64;
        #pragma unroll
        for (int k = 0; k < 16; ++k) {
            float4 hv = *(const float4*)(hp + k * 4);
            h[4 * k + 0] = hv.x; h[4 * k + 1] = hv.y;
            h[4 * k + 2] = hv.z; h[4 * k + 3] = hv.w;
        }
    }
    __syncthreads();
    const float dsk = Dskip[d];
    for (int t = 0; t < 64; ++t) {
        size_t R = (size_t)(b * 2048 + c * 64 + t);
        float dl = delta[R * 512 + d];
        float u  = uc[R * 512 + d];
        float z  = xz[R * 1024 + 512 + d];
        float du = dl * u;
        const float* bct = &sBC[t * 128];
        float y0 = 0.f, y1 = 0.f;
        #pragma unroll
        for (int n = 0; n < 64; n += 2) {
            float4 bc = *(const float4*)(bct + 2 * n);   // B_n,C_n,B_{n+1},C_{n+1}
            float e0 = __expf(dl * A[n]);
            h[n] = fmaf(e0, h[n], du * bc.x);
            y0 = fmaf(h[n], bc.y, y0);
            float e1 = __expf(dl * A[n + 1]);
            h[n + 1] = fmaf(e1, h[n + 1], du * bc.z);
            y1 = fmaf(h[n + 1], bc.w, y1);
        }
        float y = y0 + y1 + u * dsk;
        g[R * 512 + d] = y * siluf_(z);
    }
}

// ---------------- K9: transpose conv_post_w [18][256][7] -> wT [7][18][256]
__global__ void k_transpose_wpost(const float* __restrict__ w, float* __restrict__ wT)
{
    int idx = blockIdx.x * 256 + threadIdx.x;
    if (idx >= 18 * 256 * 7) return;
    int o = idx / 1792, rem = idx - o * 1792;
    int c = rem / 7, k = rem - c * 7;
    wT[k * 4608 + o * 256 + c] = w[idx];
}

// ---------------- K7: lrelu + conv_post (k=7,pad3) + exp/sin epilogue
__global__ __launch_bounds__(256) void k_conv_post(const float* __restrict__ mid,
    const float* __restrict__ wT, const float* __restrict__ bias, float* __restrict__ out)
{
    __shared__ float sX[256][40];
    __shared__ float wk[24 * 256];
    int b = blockIdx.y, t0 = blockIdx.x * 32;
    int tid = threadIdx.x;
    for (int r = 0; r < 38; ++r) {
        int ta = t0 - 3 + r;
        float v = 0.f;
        if (ta >= 0 && ta < 2048) v = lreluf_(mid[(size_t)(b * 2048 + ta) * 256 + tid]);
        sX[tid][r] = v;
    }
    int t = tid & 31, og = tid >> 5;    // 8 groups, o = og + 8j
    float acc[3];
    #pragma unroll
    for (int j = 0; j < 3; j++) { int o = og + 8 * j; acc[j] = (o < 18) ? bias[o] : 0.f; }
    for (int k = 0; k < 7; ++k) {
        __syncthreads();
        for (int idx = tid; idx < 24 * 256; idx += 256)
            wk[idx] = (idx < 18 * 256) ? wT[k * 4608 + idx] : 0.f;
        __syncthreads();
        for (int c = 0; c < 256; ++c) {
            float xv = sX[c][t + k];
            acc[0] = fmaf(xv, wk[og * 256 + c], acc[0]);
            acc[1] = fmaf(xv, wk[(og + 8) * 256 + c], acc[1]);
            acc[2] = fmaf(xv, wk[(og + 16) * 256 + c], acc[2]);
        }
    }
    int ta = t0 + t;
    #pragma unroll
    for (int j = 0; j < 3; j++) {
        int o = og + 8 * j;
        if (o >= 18) continue;
        float v = acc[j];
        if (o < 9) out[(size_t)(b * 9 + o) * 2048 + ta] = __expf(v);
        else       out[73728 + (size_t)(b * 9 + (o - 9)) * 2048 + ta] = __sinf(v);
    }
}

extern "C" void kernel_launch(void* const* d_in, const int* in_sizes, int n_in,
                              void* d_out, int out_size, void* d_ws, size_t ws_size,
                              hipStream_t stream)
{
    const float* x         = (const float*)d_in[0];
    const float* pre_w     = (const float*)d_in[1];
    const float* pre_b     = (const float*)d_in[2];
    const float* inproj_w  = (const float*)d_in[3];
    const float* dw_w      = (const float*)d_in[4];
    const float* dw_b      = (const float*)d_in[5];
    const float* xproj_w   = (const float*)d_in[6];
    const float* dt_w      = (const float*)d_in[7];
    const float* dt_b      = (const float*)d_in[8];
    const float* A_log     = (const float*)d_in[9];
    const float* Dskip     = (const float*)d_in[10];
    const float* outproj_w = (const float*)d_in[11];
    const float* post_w    = (const float*)d_in[12];
    const float* post_b    = (const float*)d_in[13];
    float* out = (float*)d_out;
    float* W = (float*)d_ws;

    float* h_pre   = W;                 //  2,097,152 floats (reused as out_mid)
    float* xz      = W + 2097152;       //  8,388,608
    float* uc      = W + 10485760;      //  4,194,304
    float* x_dbl   = W + 14680064;      //  1,179,648 (cols: dt 0..15, BC interleaved 16..143)
    float* delta   = W + 15859712;      //  4,194,304  (b,t,d)-major
    float* hloc    = W + 20054016;      //  4,063,232 (31*131072; becomes carry in-place)
    float* Pdec    = W + 24117248;      //  4,063,232
    float* g       = W + 28180480;      //  4,194,304
    float* wTpost  = W + 32374784;      //  32,256   (total 32,407,040 floats)
    float* out_mid = h_pre;

    k_conv_pre<<<dim3(128, 4), 256, 0, stream>>>(x, pre_w, pre_b, h_pre);
    k_gemm_nt<0,0><<<dim3(16, 128), 256, 0, stream>>>(h_pre, inproj_w, nullptr, xz,
                                                      8192, 1024, 256, 256, 256);
    k_dwconv<<<16384, 256, 0, stream>>>(xz, dw_w, dw_b, uc);
    k_gemm_nt<0,1><<<dim3(3, 128), 256, 0, stream>>>(uc, xproj_w, nullptr, x_dbl,
                                                     8192, 144, 512, 512, 512);
    k_gemm_nt<1,0><<<dim3(8, 128), 256, 0, stream>>>(x_dbl, dt_w, dt_b, delta,
                                                     8192, 512, 16, 144, 16);
    k_scan1<<<dim3(31, 2, 4), 256, 0, stream>>>(delta, uc, x_dbl, A_log, hloc, Pdec);
    k_carry<<<512, 256, 0, stream>>>(hloc, Pdec);
    k_scan2f<<<dim3(32, 2, 4), 256, 0, stream>>>(delta, uc, xz, x_dbl, A_log,
                                                 hloc, Dskip, g);
    k_gemm_nt<0,0><<<dim3(4, 128), 256, 0, stream>>>(g, outproj_w, nullptr, out_mid,
                                                     8192, 256, 512, 512, 512);
    k_transpose_wpost<<<126, 256, 0, stream>>>(post_w, wTpost);
    k_conv_post<<<dim3(64, 4), 256, 0, stream>>>(out_mid, wTpost, post_b, out);
}

// Round 5
// 479.002 us; speedup vs baseline: 1.6888x; 1.2073x over previous
//
#include <hip/hip_runtime.h>
#include <cstdint>

#define DEV __device__ __forceinline__

DEV float sigmoidf_(float x){ return 1.f / (1.f + __expf(-x)); }
DEV float siluf_(float x){ return x * sigmoidf_(x); }
DEV float softplusf_(float x){ return x > 20.f ? x : log1pf(__expf(x)); }
DEV float lreluf_(float x){ return x >= 0.f ? x : 0.01f * x; }

DEV unsigned short f2bf(float f){
    union { float f; uint32_t u; } v; v.f = f;
    uint32_t u = v.u;
    u += 0x7fffu + ((u >> 16) & 1u);
    return (unsigned short)(u >> 16);
}

typedef __attribute__((ext_vector_type(8))) short bf16x8;
typedef __attribute__((ext_vector_type(4))) float f32x4;

// ---------------- K1: conv_pre  x[4][80][2048] (pad3,k7) -> h_bf[4*2048][256] (bf16)
__global__ __launch_bounds__(256) void k_conv_pre(const float* __restrict__ x,
    const float* __restrict__ w, const float* __restrict__ bias,
    unsigned short* __restrict__ h_bf)
{
    const int b = blockIdx.y;
    const int t0 = blockIdx.x * 16;
    const int c = threadIdx.x;
    __shared__ float sX[80][22];
    for (int idx = threadIdx.x; idx < 80 * 22; idx += 256) {
        int m = idx / 22, tt = idx - m * 22;
        int ta = t0 - 3 + tt;
        sX[m][tt] = (ta >= 0 && ta < 2048) ? x[(b * 80 + m) * 2048 + ta] : 0.f;
    }
    __syncthreads();
    float acc[16];
    float bv = bias[c];
    #pragma unroll
    for (int i = 0; i < 16; i++) acc[i] = bv;
    const float* wrow = w + c * 560;
    for (int m = 0; m < 80; ++m) {
        float xr[22];
        #pragma unroll
        for (int q = 0; q < 22; q++) xr[q] = sX[m][q];
        #pragma unroll
        for (int k = 0; k < 7; k++) {
            float wv = wrow[m * 7 + k];
            #pragma unroll
            for (int tt = 0; tt < 16; tt++) acc[tt] = fmaf(xr[k + tt], wv, acc[tt]);
        }
    }
    for (int tt = 0; tt < 16; tt++)
        h_bf[(b * 2048 + t0 + tt) * 256 + c] = f2bf(acc[tt]);
}

// ---------------- pack fp32 -> bf16 (weights)
__global__ void k_pack_bf16(const float* __restrict__ src, unsigned short* __restrict__ dst, int n)
{
    int i = blockIdx.x * 256 + threadIdx.x;
    if (i < n) dst[i] = f2bf(src[i]);
}

// ---------------- bf16 MFMA NT GEMM: C[m,n] = dot(A[m,:K], B[n,:K]), fp32 out.
// A [M][K] bf16 row-major, B [N][K] bf16 row-major. M%64==0, K%64==0.
// PERM: 1 -> x_dbl column interleave (dt | B/C interleaved)
template<int PERM>
__global__ __launch_bounds__(256) void k_gemm_mfma(const unsigned short* __restrict__ A,
    const unsigned short* __restrict__ B, float* __restrict__ C, int M, int N, int K)
{
    __shared__ unsigned short As[64][72];   // +8 pad breaks pow2 bank stride
    __shared__ unsigned short Bs[64][72];
    const int tid = threadIdx.x;
    const int bm = blockIdx.y * 64, bn = blockIdx.x * 64;
    const int w = tid >> 6, lane = tid & 63;
    const int l16 = lane & 15, quad = lane >> 4;
    const int lrow = tid >> 3, lcol = tid & 7;
    f32x4 acc[4] = {};
    for (int k0 = 0; k0 < K; k0 += 64) {
        __syncthreads();
        #pragma unroll
        for (int hh = 0; hh < 2; ++hh) {
            int r = lrow + 32 * hh;
            *(uint4*)&As[r][lcol * 8] = *(const uint4*)(A + (size_t)(bm + r) * K + k0 + lcol * 8);
            uint4 bvv = make_uint4(0, 0, 0, 0);
            if (bn + r < N) bvv = *(const uint4*)(B + (size_t)(bn + r) * K + k0 + lcol * 8);
            *(uint4*)&Bs[r][lcol * 8] = bvv;
        }
        __syncthreads();
        #pragma unroll
        for (int kk = 0; kk < 64; kk += 32) {
            bf16x8 af = *(const bf16x8*)&As[w * 16 + l16][kk + quad * 8];
            #pragma unroll
            for (int nt = 0; nt < 4; ++nt) {
                bf16x8 bfr = *(const bf16x8*)&Bs[nt * 16 + l16][kk + quad * 8];
                acc[nt] = __builtin_amdgcn_mfma_f32_16x16x32_bf16(af, bfr, acc[nt], 0, 0, 0);
            }
        }
    }
    #pragma unroll
    for (int nt = 0; nt < 4; ++nt) {
        #pragma unroll
        for (int i = 0; i < 4; ++i) {
            int m = bm + w * 16 + quad * 4 + i;
            int n = bn + nt * 16 + l16;
            if (n < N) {
                int nn = n;
                if (PERM) nn = (n < 16) ? n : (n < 80 ? 16 + 2 * (n - 16) : 17 + 2 * (n - 80));
                C[(size_t)m * N + nn] = acc[nt][i];
            }
        }
    }
}

// ---------------- fp32 NT GEMM (dt_proj only): softplus epilogue
template<int ACT, int PERM>
__global__ __launch_bounds__(256) void k_gemm_nt(const float* __restrict__ A,
    const float* __restrict__ B, const float* __restrict__ bias, float* __restrict__ C,
    int M, int N, int K, int lda, int ldb)
{
    __shared__ float As[16][64];
    __shared__ float Bs[16][64];
    const int bm = blockIdx.y * 64, bn = blockIdx.x * 64;
    const int tid = threadIdx.x;
    const int lm = tid >> 2, lk = (tid & 3) * 4;
    const int tx = tid & 15, ty = tid >> 4;
    float acc[4][4];
    #pragma unroll
    for (int i = 0; i < 4; i++)
        #pragma unroll
        for (int j = 0; j < 4; j++) acc[i][j] = 0.f;
    for (int k0 = 0; k0 < K; k0 += 16) {
        float4 av = make_float4(0.f,0.f,0.f,0.f), bv = make_float4(0.f,0.f,0.f,0.f);
        if (bm + lm < M) av = *(const float4*)(A + (size_t)(bm + lm) * lda + k0 + lk);
        if (bn + lm < N) bv = *(const float4*)(B + (size_t)(bn + lm) * ldb + k0 + lk);
        __syncthreads();
        As[lk + 0][lm] = av.x; As[lk + 1][lm] = av.y; As[lk + 2][lm] = av.z; As[lk + 3][lm] = av.w;
        Bs[lk + 0][lm] = bv.x; Bs[lk + 1][lm] = bv.y; Bs[lk + 2][lm] = bv.z; Bs[lk + 3][lm] = bv.w;
        __syncthreads();
        #pragma unroll
        for (int kk = 0; kk < 16; kk++) {
            float4 a  = *(const float4*)&As[kk][ty * 4];
            float4 b4 = *(const float4*)&Bs[kk][tx * 4];
            acc[0][0] = fmaf(a.x, b4.x, acc[0][0]); acc[0][1] = fmaf(a.x, b4.y, acc[0][1]);
            acc[0][2] = fmaf(a.x, b4.z, acc[0][2]); acc[0][3] = fmaf(a.x, b4.w, acc[0][3]);
            acc[1][0] = fmaf(a.y, b4.x, acc[1][0]); acc[1][1] = fmaf(a.y, b4.y, acc[1][1]);
            acc[1][2] = fmaf(a.y, b4.z, acc[1][2]); acc[1][3] = fmaf(a.y, b4.w, acc[1][3]);
            acc[2][0] = fmaf(a.z, b4.x, acc[2][0]); acc[2][1] = fmaf(a.z, b4.y, acc[2][1]);
            acc[2][2] = fmaf(a.z, b4.z, acc[2][2]); acc[2][3] = fmaf(a.z, b4.w, acc[2][3]);
            acc[3][0] = fmaf(a.w, b4.x, acc[3][0]); acc[3][1] = fmaf(a.w, b4.y, acc[3][1]);
            acc[3][2] = fmaf(a.w, b4.z, acc[3][2]); acc[3][3] = fmaf(a.w, b4.w, acc[3][3]);
        }
    }
    #pragma unroll
    for (int i = 0; i < 4; i++) {
        int m = bm + ty * 4 + i;
        if (m >= M) continue;
        #pragma unroll
        for (int j = 0; j < 4; j++) {
            int n = bn + tx * 4 + j;
            if (n >= N) continue;
            float v = acc[i][j];
            if (bias) v += bias[n];
            if (ACT == 1) v = softplusf_(v);
            int nn = n;
            if (PERM) nn = (n < 16) ? n : (n < 80 ? 16 + 2 * (n - 16) : 17 + 2 * (n - 80));
            C[(size_t)m * N + nn] = v;
        }
    }
}

// ---------------- K3: causal depthwise conv (k=4) + SiLU. writes fp32 + bf16
__global__ __launch_bounds__(256) void k_dwconv(const float* __restrict__ xz,
    const float* __restrict__ w, const float* __restrict__ bias,
    float* __restrict__ uc, unsigned short* __restrict__ uc_bf)
{
    int idx = blockIdx.x * 256 + threadIdx.x;     // = i*512 + d
    int i = idx >> 9, d = idx & 511;
    int b = i >> 11, t = i & 2047;
    float4 wv = *(const float4*)(w + d * 4);
    float wk[4] = {wv.x, wv.y, wv.z, wv.w};
    float acc = bias[d];
    const float* base = xz + (size_t)(b * 2048) * 1024 + d;
    #pragma unroll
    for (int k = 0; k < 4; k++) {
        int tt = t - 3 + k;
        if (tt >= 0) acc = fmaf(base[(size_t)tt * 1024], wk[k], acc);
    }
    float s = siluf_(acc);
    uc[idx] = s;
    uc_bf[idx] = f2bf(s);
}

// ---------------- K5a: scan pass 1 — 63 chunks of 32 t, lane = d, 64 states
// in registers, B tile in LDS. Outputs hloc[c][bd][n] + sumd[c][bd].
__global__ __launch_bounds__(256, 1) void k_scan1(const float* __restrict__ delta,
    const float* __restrict__ uc, const float* __restrict__ xdbl,
    const float* __restrict__ A_log, float* __restrict__ hloc, float* __restrict__ sumdg)
{
    __shared__ float sBC[32 * 128];             // 32 t x (B,C interleaved 128 floats)
    const int tid = threadIdx.x;
    const int c = blockIdx.x, b = blockIdx.z;
    const int d = blockIdx.y * 256 + tid;
    for (int idx = tid; idx < 1024; idx += 256) {
        int r = idx >> 5, q = idx & 31;
        *(float4*)&sBC[r * 128 + q * 4] =
            *(const float4*)(xdbl + (size_t)(b * 2048 + c * 32 + r) * 144 + 16 + q * 4);
    }
    float A[64], h[64];
    #pragma unroll
    for (int k = 0; k < 16; ++k) {
        float4 al = *(const float4*)(A_log + (size_t)d * 64 + k * 4);
        A[4 * k + 0] = -__expf(al.x); A[4 * k + 1] = -__expf(al.y);
        A[4 * k + 2] = -__expf(al.z); A[4 * k + 3] = -__expf(al.w);
    }
    #pragma unroll
    for (int n = 0; n < 64; ++n) h[n] = 0.f;
    __syncthreads();
    const float* pD = delta + (size_t)(b * 2048 + c * 32) * 512 + d;
    const float* pU = uc    + (size_t)(b * 2048 + c * 32) * 512 + d;
    float sumd = 0.f;
    for (int t = 0; t < 32; ++t) {
        float dl = pD[(size_t)t * 512];
        float u  = pU[(size_t)t * 512];
        float du = dl * u;
        sumd += dl;
        const float* bct = &sBC[t * 128];
        #pragma unroll
        for (int n = 0; n < 64; n += 2) {
            float4 bc = *(const float4*)(bct + 2 * n);   // B_n,C_n,B_{n+1},C_{n+1}
            h[n]     = fmaf(__expf(dl * A[n]),     h[n],     du * bc.x);
            h[n + 1] = fmaf(__expf(dl * A[n + 1]), h[n + 1], du * bc.z);
        }
    }
    float* hp = hloc + ((size_t)c * 2048 + b * 512 + d) * 64;
    #pragma unroll
    for (int n = 0; n < 64; n += 4)
        *(float4*)(hp + n) = make_float4(h[n], h[n + 1], h[n + 2], h[n + 3]);
    sumdg[(size_t)c * 2048 + b * 512 + d] = sumd;
}

// ---------------- K5b: sequential carry across 63 chunks, in-place into hloc.
// P recomputed from sumd. After: hloc[c] = inclusive carry through chunk c.
__global__ __launch_bounds__(256) void k_carry(float* __restrict__ hloc,
    const float* __restrict__ sumdg, const float* __restrict__ A_log)
{
    int tid = blockIdx.x * 256 + threadIdx.x;   // bd*64 + n, 131072 total
    int bd = tid >> 6, n = tid & 63, d = bd & 511;
    float A = -__expf(A_log[d * 64 + n]);
    float carry = hloc[tid];                    // chunk 0
    for (int cc = 1; cc < 63; ++cc) {
        float P = __expf(sumdg[(size_t)cc * 2048 + bd] * A);
        size_t o = (size_t)cc * 131072 + tid;
        carry = fmaf(carry, P, hloc[o]);
        hloc[o] = carry;
    }
}

// ---------------- K5c: scan pass 2 — 64 chunks of 32 t, lane = d. Fused
// combine epilogue: g = (y + u*Dskip)*silu(z), written (b,t,d)-major as bf16.
__global__ __launch_bounds__(256, 1) void k_scan2f(const float* __restrict__ delta,
    const float* __restrict__ uc, const float* __restrict__ xz,
    const float* __restrict__ xdbl, const float* __restrict__ A_log,
    const float* __restrict__ hcar, const float* __restrict__ Dskip,
    unsigned short* __restrict__ g_bf)
{
    __shared__ float sBC[32 * 128];
    const int tid = threadIdx.x;
    const int c = blockIdx.x, b = blockIdx.z;
    const int d = blockIdx.y * 256 + tid;
    for (int idx = tid; idx < 1024; idx += 256) {
        int r = idx >> 5, q = idx & 31;
        *(float4*)&sBC[r * 128 + q * 4] =
            *(const float4*)(xdbl + (size_t)(b * 2048 + c * 32 + r) * 144 + 16 + q * 4);
    }
    float A[64], h[64];
    #pragma unroll
    for (int k = 0; k < 16; ++k) {
        float4 al = *(const float4*)(A_log + (size_t)d * 64 + k * 4);
        A[4 * k + 0] = -__expf(al.x); A[4 * k + 1] = -__expf(al.y);
        A[4 * k + 2] = -__expf(al.z); A[4 * k + 3] = -__expf(al.w);
    }
    if (c == 0) {
        #pragma unroll
        for (int n = 0; n < 64; ++n) h[n] = 0.f;
    } else {
        const float* hp = hcar + ((size_t)(c - 1) * 2048 + b * 512 + d) * 64;
        #pragma unroll
        for (int k = 0; k < 16; ++k) {
            float4 hv = *(const float4*)(hp + k * 4);
            h[4 * k + 0] = hv.x; h[4 * k + 1] = hv.y;
            h[4 * k + 2] = hv.z; h[4 * k + 3] = hv.w;
        }
    }
    __syncthreads();
    const float dsk = Dskip[d];
    for (int t = 0; t < 32; ++t) {
        size_t R = (size_t)(b * 2048 + c * 32 + t);
        float dl = delta[R * 512 + d];
        float u  = uc[R * 512 + d];
        float z  = xz[R * 1024 + 512 + d];
        float du = dl * u;
        const float* bct = &sBC[t * 128];
        float y0 = 0.f, y1 = 0.f;
        #pragma unroll
        for (int n = 0; n < 64; n += 2) {
            float4 bc = *(const float4*)(bct + 2 * n);
            float e0 = __expf(dl * A[n]);
            h[n] = fmaf(e0, h[n], du * bc.x);
            y0 = fmaf(h[n], bc.y, y0);
            float e1 = __expf(dl * A[n + 1]);
            h[n + 1] = fmaf(e1, h[n + 1], du * bc.z);
            y1 = fmaf(h[n + 1], bc.w, y1);
        }
        float y = y0 + y1 + u * dsk;
        g_bf[R * 512 + d] = f2bf(y * siluf_(z));
    }
}

// ---------------- K9: transpose conv_post_w [18][256][7] -> wT [7][18][256]
__global__ void k_transpose_wpost(const float* __restrict__ w, float* __restrict__ wT)
{
    int idx = blockIdx.x * 256 + threadIdx.x;
    if (idx >= 18 * 256 * 7) return;
    int o = idx / 1792, rem = idx - o * 1792;
    int c = rem / 7, k = rem - c * 7;
    wT[k * 4608 + o * 256 + c] = w[idx];
}

// ---------------- K7: lrelu + conv_post (k=7,pad3) + exp/sin epilogue
__global__ __launch_bounds__(256) void k_conv_post(const float* __restrict__ mid,
    const float* __restrict__ wT, const float* __restrict__ bias, float* __restrict__ out)
{
    __shared__ float sX[256][40];
    __shared__ float wk[24 * 256];
    int b = blockIdx.y, t0 = blockIdx.x * 32;
    int tid = threadIdx.x;
    for (int r = 0; r < 38; ++r) {
        int ta = t0 - 3 + r;
        float v = 0.f;
        if (ta >= 0 && ta < 2048) v = lreluf_(mid[(size_t)(b * 2048 + ta) * 256 + tid]);
        sX[tid][r] = v;
    }
    int t = tid & 31, og = tid >> 5;
    float acc[3];
    #pragma unroll
    for (int j = 0; j < 3; j++) { int o = og + 8 * j; acc[j] = (o < 18) ? bias[o] : 0.f; }
    for (int k = 0; k < 7; ++k) {
        __syncthreads();
        for (int idx = tid; idx < 24 * 256; idx += 256)
            wk[idx] = (idx < 18 * 256) ? wT[k * 4608 + idx] : 0.f;
        __syncthreads();
        for (int c = 0; c < 256; ++c) {
            float xv = sX[c][t + k];
            acc[0] = fmaf(xv, wk[og * 256 + c], acc[0]);
            acc[1] = fmaf(xv, wk[(og + 8) * 256 + c], acc[1]);
            acc[2] = fmaf(xv, wk[(og + 16) * 256 + c], acc[2]);
        }
    }
    int ta = t0 + t;
    #pragma unroll
    for (int j = 0; j < 3; j++) {
        int o = og + 8 * j;
        if (o >= 18) continue;
        float v = acc[j];
        if (o < 9) out[(size_t)(b * 9 + o) * 2048 + ta] = __expf(v);
        else       out[73728 + (size_t)(b * 9 + (o - 9)) * 2048 + ta] = __sinf(v);
    }
}

extern "C" void kernel_launch(void* const* d_in, const int* in_sizes, int n_in,
                              void* d_out, int out_size, void* d_ws, size_t ws_size,
                              hipStream_t stream)
{
    const float* x         = (const float*)d_in[0];
    const float* pre_w     = (const float*)d_in[1];
    const float* pre_b     = (const float*)d_in[2];
    const float* inproj_w  = (const float*)d_in[3];
    const float* dw_w      = (const float*)d_in[4];
    const float* dw_b      = (const float*)d_in[5];
    const float* xproj_w   = (const float*)d_in[6];
    const float* dt_w      = (const float*)d_in[7];
    const float* dt_b      = (const float*)d_in[8];
    const float* A_log     = (const float*)d_in[9];
    const float* Dskip     = (const float*)d_in[10];
    const float* outproj_w = (const float*)d_in[11];
    const float* post_w    = (const float*)d_in[12];
    const float* post_b    = (const float*)d_in[13];
    float* out = (float*)d_out;
    float* W = (float*)d_ws;

    float* xz      = W;                 //  8,388,608 fp32
    float* uc      = W + 8388608;       //  4,194,304 fp32
    float* x_dbl   = W + 12582912;      //  1,179,648 fp32
    float* delta   = W + 13762560;      //  4,194,304 fp32 (b,t,d)-major
    float* hloc    = W + 17956864;      //  8,257,536 (63*131072; carry in-place;
                                        //             reused as out_mid after scan2f)
    float* sumd    = W + 26214400;      //    129,024 (63*2048)
    float* wTpost  = W + 26343424;      //     32,256
    unsigned short* h_bf  = (unsigned short*)(W + 26375680);  // 2,097,152 ush
    unsigned short* uc_bf = (unsigned short*)(W + 27424256);  // 4,194,304 ush
    unsigned short* g_bf  = (unsigned short*)(W + 29521408);  // 4,194,304 ush
    unsigned short* wbf_i = (unsigned short*)(W + 31618560);  //   262,144 ush
    unsigned short* wbf_x = wbf_i + 262144;                   //    73,728 ush
    unsigned short* wbf_o = wbf_x + 73728;                    //   131,072 ush
    float* out_mid = hloc;              // alias: hloc dead after scan2f

    k_pack_bf16<<<1024, 256, 0, stream>>>(inproj_w, wbf_i, 262144);
    k_pack_bf16<<<288, 256, 0, stream>>>(xproj_w, wbf_x, 73728);
    k_pack_bf16<<<512, 256, 0, stream>>>(outproj_w, wbf_o, 131072);
    k_conv_pre<<<dim3(128, 4), 256, 0, stream>>>(x, pre_w, pre_b, h_bf);
    k_gemm_mfma<0><<<dim3(16, 128), 256, 0, stream>>>(h_bf, wbf_i, xz, 8192, 1024, 256);
    k_dwconv<<<16384, 256, 0, stream>>>(xz, dw_w, dw_b, uc, uc_bf);
    k_gemm_mfma<1><<<dim3(3, 128), 256, 0, stream>>>(uc_bf, wbf_x, x_dbl, 8192, 144, 512);
    k_gemm_nt<1,0><<<dim3(8, 128), 256, 0, stream>>>(x_dbl, dt_w, dt_b, delta,
                                                     8192, 512, 16, 144, 16);
    k_scan1<<<dim3(63, 2, 4), 256, 0, stream>>>(delta, uc, x_dbl, A_log, hloc, sumd);
    k_carry<<<512, 256, 0, stream>>>(hloc, sumd, A_log);
    k_scan2f<<<dim3(64, 2, 4), 256, 0, stream>>>(delta, uc, xz, x_dbl, A_log,
                                                 hloc, Dskip, g_bf);
    k_gemm_mfma<0><<<dim3(4, 128), 256, 0, stream>>>(g_bf, wbf_o, out_mid, 8192, 256, 512);
    k_transpose_wpost<<<126, 256, 0, stream>>>(post_w, wTpost);
    k_conv_post<<<dim3(64, 4), 256, 0, stream>>>(out_mid, wTpost, post_b, out);
}

// Round 6
// 445.977 us; speedup vs baseline: 1.8138x; 1.0741x over previous
//
#include <hip/hip_runtime.h>
#include <cstdint>

#define DEV __device__ __forceinline__

DEV float sigmoidf_(float x){ return 1.f / (1.f + __expf(-x)); }
DEV float siluf_(float x){ return x * sigmoidf_(x); }
DEV float softplusf_(float x){ return x > 20.f ? x : log1pf(__expf(x)); }
DEV float lreluf_(float x){ return x >= 0.f ? x : 0.01f * x; }

DEV unsigned short f2bf(float f){
    union { float f; uint32_t u; } v; v.f = f;
    uint32_t u = v.u;
    u += 0x7fffu + ((u >> 16) & 1u);
    return (unsigned short)(u >> 16);
}

typedef __attribute__((ext_vector_type(8))) short bf16x8;
typedef __attribute__((ext_vector_type(4))) float f32x4;

// ---------------- K1: conv_pre  x[4][80][2048] (pad3,k7) -> h_bf[4*2048][256] (bf16)
__global__ __launch_bounds__(256) void k_conv_pre(const float* __restrict__ x,
    const float* __restrict__ w, const float* __restrict__ bias,
    unsigned short* __restrict__ h_bf)
{
    const int b = blockIdx.y;
    const int t0 = blockIdx.x * 16;
    const int c = threadIdx.x;
    __shared__ float sX[80][22];
    for (int idx = threadIdx.x; idx < 80 * 22; idx += 256) {
        int m = idx / 22, tt = idx - m * 22;
        int ta = t0 - 3 + tt;
        sX[m][tt] = (ta >= 0 && ta < 2048) ? x[(b * 80 + m) * 2048 + ta] : 0.f;
    }
    __syncthreads();
    float acc[16];
    float bv = bias[c];
    #pragma unroll
    for (int i = 0; i < 16; i++) acc[i] = bv;
    const float* wrow = w + c * 560;
    for (int m = 0; m < 80; ++m) {
        float xr[22];
        #pragma unroll
        for (int q = 0; q < 22; q++) xr[q] = sX[m][q];
        #pragma unroll
        for (int k = 0; k < 7; k++) {
            float wv = wrow[m * 7 + k];
            #pragma unroll
            for (int tt = 0; tt < 16; tt++) acc[tt] = fmaf(xr[k + tt], wv, acc[tt]);
        }
    }
    for (int tt = 0; tt < 16; tt++)
        h_bf[(b * 2048 + t0 + tt) * 256 + c] = f2bf(acc[tt]);
}

// ---------------- pack fp32 -> bf16 (weights)
__global__ void k_pack_bf16(const float* __restrict__ src, unsigned short* __restrict__ dst, int n)
{
    int i = blockIdx.x * 256 + threadIdx.x;
    if (i < n) dst[i] = f2bf(src[i]);
}

// ---------------- bf16 MFMA NT GEMM: C[m,n] = dot(A[m,:K], B[n,:K]), fp32 out.
// A [M][K] bf16 row-major, B [N][K] bf16 row-major. M%64==0, K%64==0.
// PERM: 1 -> x_dbl column interleave (dt | B/C interleaved)
template<int PERM>
__global__ __launch_bounds__(256) void k_gemm_mfma(const unsigned short* __restrict__ A,
    const unsigned short* __restrict__ B, float* __restrict__ C, int M, int N, int K)
{
    __shared__ unsigned short As[64][72];   // +8 pad breaks pow2 bank stride
    __shared__ unsigned short Bs[64][72];
    const int tid = threadIdx.x;
    const int bm = blockIdx.y * 64, bn = blockIdx.x * 64;
    const int w = tid >> 6, lane = tid & 63;
    const int l16 = lane & 15, quad = lane >> 4;
    const int lrow = tid >> 3, lcol = tid & 7;
    f32x4 acc[4] = {};
    for (int k0 = 0; k0 < K; k0 += 64) {
        __syncthreads();
        #pragma unroll
        for (int hh = 0; hh < 2; ++hh) {
            int r = lrow + 32 * hh;
            *(uint4*)&As[r][lcol * 8] = *(const uint4*)(A + (size_t)(bm + r) * K + k0 + lcol * 8);
            uint4 bvv = make_uint4(0, 0, 0, 0);
            if (bn + r < N) bvv = *(const uint4*)(B + (size_t)(bn + r) * K + k0 + lcol * 8);
            *(uint4*)&Bs[r][lcol * 8] = bvv;
        }
        __syncthreads();
        #pragma unroll
        for (int kk = 0; kk < 64; kk += 32) {
            bf16x8 af = *(const bf16x8*)&As[w * 16 + l16][kk + quad * 8];
            #pragma unroll
            for (int nt = 0; nt < 4; ++nt) {
                bf16x8 bfr = *(const bf16x8*)&Bs[nt * 16 + l16][kk + quad * 8];
                acc[nt] = __builtin_amdgcn_mfma_f32_16x16x32_bf16(af, bfr, acc[nt], 0, 0, 0);
            }
        }
    }
    #pragma unroll
    for (int nt = 0; nt < 4; ++nt) {
        #pragma unroll
        for (int i = 0; i < 4; ++i) {
            int m = bm + w * 16 + quad * 4 + i;
            int n = bn + nt * 16 + l16;
            if (n < N) {
                int nn = n;
                if (PERM) nn = (n < 16) ? n : (n < 80 ? 16 + 2 * (n - 16) : 17 + 2 * (n - 80));
                C[(size_t)m * N + nn] = acc[nt][i];
            }
        }
    }
}

// ---------------- fp32 NT GEMM (dt_proj only): softplus epilogue
template<int ACT, int PERM>
__global__ __launch_bounds__(256) void k_gemm_nt(const float* __restrict__ A,
    const float* __restrict__ B, const float* __restrict__ bias, float* __restrict__ C,
    int M, int N, int K, int lda, int ldb)
{
    __shared__ float As[16][64];
    __shared__ float Bs[16][64];
    const int bm = blockIdx.y * 64, bn = blockIdx.x * 64;
    const int tid = threadIdx.x;
    const int lm = tid >> 2, lk = (tid & 3) * 4;
    const int tx = tid & 15, ty = tid >> 4;
    float acc[4][4];
    #pragma unroll
    for (int i = 0; i < 4; i++)
        #pragma unroll
        for (int j = 0; j < 4; j++) acc[i][j] = 0.f;
    for (int k0 = 0; k0 < K; k0 += 16) {
        float4 av = make_float4(0.f,0.f,0.f,0.f), bv = make_float4(0.f,0.f,0.f,0.f);
        if (bm + lm < M) av = *(const float4*)(A + (size_t)(bm + lm) * lda + k0 + lk);
        if (bn + lm < N) bv = *(const float4*)(B + (size_t)(bn + lm) * ldb + k0 + lk);
        __syncthreads();
        As[lk + 0][lm] = av.x; As[lk + 1][lm] = av.y; As[lk + 2][lm] = av.z; As[lk + 3][lm] = av.w;
        Bs[lk + 0][lm] = bv.x; Bs[lk + 1][lm] = bv.y; Bs[lk + 2][lm] = bv.z; Bs[lk + 3][lm] = bv.w;
        __syncthreads();
        #pragma unroll
        for (int kk = 0; kk < 16; kk++) {
            float4 a  = *(const float4*)&As[kk][ty * 4];
            float4 b4 = *(const float4*)&Bs[kk][tx * 4];
            acc[0][0] = fmaf(a.x, b4.x, acc[0][0]); acc[0][1] = fmaf(a.x, b4.y, acc[0][1]);
            acc[0][2] = fmaf(a.x, b4.z, acc[0][2]); acc[0][3] = fmaf(a.x, b4.w, acc[0][3]);
            acc[1][0] = fmaf(a.y, b4.x, acc[1][0]); acc[1][1] = fmaf(a.y, b4.y, acc[1][1]);
            acc[1][2] = fmaf(a.y, b4.z, acc[1][2]); acc[1][3] = fmaf(a.y, b4.w, acc[1][3]);
            acc[2][0] = fmaf(a.z, b4.x, acc[2][0]); acc[2][1] = fmaf(a.z, b4.y, acc[2][1]);
            acc[2][2] = fmaf(a.z, b4.z, acc[2][2]); acc[2][3] = fmaf(a.z, b4.w, acc[2][3]);
            acc[3][0] = fmaf(a.w, b4.x, acc[3][0]); acc[3][1] = fmaf(a.w, b4.y, acc[3][1]);
            acc[3][2] = fmaf(a.w, b4.z, acc[3][2]); acc[3][3] = fmaf(a.w, b4.w, acc[3][3]);
        }
    }
    #pragma unroll
    for (int i = 0; i < 4; i++) {
        int m = bm + ty * 4 + i;
        if (m >= M) continue;
        #pragma unroll
        for (int j = 0; j < 4; j++) {
            int n = bn + tx * 4 + j;
            if (n >= N) continue;
            float v = acc[i][j];
            if (bias) v += bias[n];
            if (ACT == 1) v = softplusf_(v);
            int nn = n;
            if (PERM) nn = (n < 16) ? n : (n < 80 ? 16 + 2 * (n - 16) : 17 + 2 * (n - 80));
            C[(size_t)m * N + nn] = v;
        }
    }
}

// ---------------- K3: causal depthwise conv (k=4) + SiLU. writes fp32 + bf16
__global__ __launch_bounds__(256) void k_dwconv(const float* __restrict__ xz,
    const float* __restrict__ w, const float* __restrict__ bias,
    float* __restrict__ uc, unsigned short* __restrict__ uc_bf)
{
    int idx = blockIdx.x * 256 + threadIdx.x;     // = i*512 + d
    int i = idx >> 9, d = idx & 511;
    int b = i >> 11, t = i & 2047;
    float4 wv = *(const float4*)(w + d * 4);
    float wk[4] = {wv.x, wv.y, wv.z, wv.w};
    float acc = bias[d];
    const float* base = xz + (size_t)(b * 2048) * 1024 + d;
    #pragma unroll
    for (int k = 0; k < 4; k++) {
        int tt = t - 3 + k;
        if (tt >= 0) acc = fmaf(base[(size_t)tt * 1024], wk[k], acc);
    }
    float s = siluf_(acc);
    uc[idx] = s;
    uc_bf[idx] = f2bf(s);
}

// ---------------- K5a: scan pass 1 — 63 chunks of 32 t. Thread = (d, n-half):
// 32 states in registers, wave = 32 d x 2 halves. B/C tile in LDS (broadcast).
// Outputs hloc[c][bd][n] + sumd[c][bd].
__global__ __launch_bounds__(256, 4) void k_scan1(const float* __restrict__ delta,
    const float* __restrict__ uc, const float* __restrict__ xdbl,
    const float* __restrict__ A_log, float* __restrict__ hloc, float* __restrict__ sumdg)
{
    __shared__ float sBC[32 * 128];             // 32 t x (B,C interleaved 128 floats)
    const int tid = threadIdx.x;
    const int c = blockIdx.x, dg = blockIdx.y, b = blockIdx.z;
    const int w = tid >> 6, lane = tid & 63;
    const int dl5 = lane & 31, half = lane >> 5;
    const int d = dg * 128 + w * 32 + dl5;
    const int nbase = half * 32;
    for (int idx = tid; idx < 1024; idx += 256) {
        int r = idx >> 5, q = idx & 31;
        *(float4*)&sBC[r * 128 + q * 4] =
            *(const float4*)(xdbl + (size_t)(b * 2048 + c * 32 + r) * 144 + 16 + q * 4);
    }
    float A[32], h[32];
    #pragma unroll
    for (int k = 0; k < 8; ++k) {
        float4 al = *(const float4*)(A_log + (size_t)d * 64 + nbase + k * 4);
        A[4 * k + 0] = -__expf(al.x); A[4 * k + 1] = -__expf(al.y);
        A[4 * k + 2] = -__expf(al.z); A[4 * k + 3] = -__expf(al.w);
    }
    #pragma unroll
    for (int n = 0; n < 32; ++n) h[n] = 0.f;
    __syncthreads();
    const float* pD = delta + (size_t)(b * 2048 + c * 32) * 512 + d;
    const float* pU = uc    + (size_t)(b * 2048 + c * 32) * 512 + d;
    float sumd = 0.f;
    for (int t = 0; t < 32; ++t) {
        float dl = pD[(size_t)t * 512];
        float u  = pU[(size_t)t * 512];
        float du = dl * u;
        sumd += dl;
        const float* bct = &sBC[t * 128 + half * 64];
        #pragma unroll
        for (int n = 0; n < 32; n += 2) {
            float4 bc = *(const float4*)(bct + 2 * n);   // B_n,C_n,B_{n+1},C_{n+1}
            h[n]     = fmaf(__expf(dl * A[n]),     h[n],     du * bc.x);
            h[n + 1] = fmaf(__expf(dl * A[n + 1]), h[n + 1], du * bc.z);
        }
    }
    float* hp = hloc + ((size_t)c * 2048 + b * 512 + d) * 64 + nbase;
    #pragma unroll
    for (int n = 0; n < 32; n += 4)
        *(float4*)(hp + n) = make_float4(h[n], h[n + 1], h[n + 2], h[n + 3]);
    if (half == 0)
        sumdg[(size_t)c * 2048 + b * 512 + d] = sumd;
}

// ---------------- K5b: sequential carry across 63 chunks, in-place into hloc.
// P recomputed from sumd. After: hloc[c] = inclusive carry through chunk c.
__global__ __launch_bounds__(256) void k_carry(float* __restrict__ hloc,
    const float* __restrict__ sumdg, const float* __restrict__ A_log)
{
    int tid = blockIdx.x * 256 + threadIdx.x;   // bd*64 + n, 131072 total
    int bd = tid >> 6, n = tid & 63, d = bd & 511;
    float A = -__expf(A_log[d * 64 + n]);
    float carry = hloc[tid];                    // chunk 0
    for (int cc = 1; cc < 63; ++cc) {
        float P = __expf(sumdg[(size_t)cc * 2048 + bd] * A);
        size_t o = (size_t)cc * 131072 + tid;
        carry = fmaf(carry, P, hloc[o]);
        hloc[o] = carry;
    }
}

// ---------------- K5c: scan pass 2 — 64 chunks of 32 t. Thread = (d, n-half),
// y combined via one shfl_xor(32). Fused epilogue: g = (y+u*Dskip)*silu(z),
// written (b,t,d)-major as bf16.
__global__ __launch_bounds__(256, 4) void k_scan2f(const float* __restrict__ delta,
    const float* __restrict__ uc, const float* __restrict__ xz,
    const float* __restrict__ xdbl, const float* __restrict__ A_log,
    const float* __restrict__ hcar, const float* __restrict__ Dskip,
    unsigned short* __restrict__ g_bf)
{
    __shared__ float sBC[32 * 128];
    const int tid = threadIdx.x;
    const int c = blockIdx.x, dg = blockIdx.y, b = blockIdx.z;
    const int w = tid >> 6, lane = tid & 63;
    const int dl5 = lane & 31, half = lane >> 5;
    const int d = dg * 128 + w * 32 + dl5;
    const int nbase = half * 32;
    for (int idx = tid; idx < 1024; idx += 256) {
        int r = idx >> 5, q = idx & 31;
        *(float4*)&sBC[r * 128 + q * 4] =
            *(const float4*)(xdbl + (size_t)(b * 2048 + c * 32 + r) * 144 + 16 + q * 4);
    }
    float A[32], h[32];
    #pragma unroll
    for (int k = 0; k < 8; ++k) {
        float4 al = *(const float4*)(A_log + (size_t)d * 64 + nbase + k * 4);
        A[4 * k + 0] = -__expf(al.x); A[4 * k + 1] = -__expf(al.y);
        A[4 * k + 2] = -__expf(al.z); A[4 * k + 3] = -__expf(al.w);
    }
    if (c == 0) {
        #pragma unroll
        for (int n = 0; n < 32; ++n) h[n] = 0.f;
    } else {
        const float* hp = hcar + ((size_t)(c - 1) * 2048 + b * 512 + d) * 64 + nbase;
        #pragma unroll
        for (int k = 0; k < 8; ++k) {
            float4 hv = *(const float4*)(hp + k * 4);
            h[4 * k + 0] = hv.x; h[4 * k + 1] = hv.y;
            h[4 * k + 2] = hv.z; h[4 * k + 3] = hv.w;
        }
    }
    __syncthreads();
    const float dsk = Dskip[d];
    for (int t = 0; t < 32; ++t) {
        size_t R = (size_t)(b * 2048 + c * 32 + t);
        float dl = delta[R * 512 + d];
        float u  = uc[R * 512 + d];
        float z  = xz[R * 1024 + 512 + d];
        float du = dl * u;
        const float* bct = &sBC[t * 128 + half * 64];
        float y0 = 0.f, y1 = 0.f;
        #pragma unroll
        for (int n = 0; n < 32; n += 2) {
            float4 bc = *(const float4*)(bct + 2 * n);
            float e0 = __expf(dl * A[n]);
            h[n] = fmaf(e0, h[n], du * bc.x);
            y0 = fmaf(h[n], bc.y, y0);
            float e1 = __expf(dl * A[n + 1]);
            h[n + 1] = fmaf(e1, h[n + 1], du * bc.z);
            y1 = fmaf(h[n + 1], bc.w, y1);
        }
        float yh = y0 + y1;
        yh += __shfl_xor(yh, 32, 64);           // combine the two n-halves
        if (half == 0) {
            float y = yh + u * dsk;
            g_bf[R * 512 + d] = f2bf(y * siluf_(z));
        }
    }
}

// ---------------- K9: transpose conv_post_w [18][256][7] -> wT [7][18][256]
__global__ void k_transpose_wpost(const float* __restrict__ w, float* __restrict__ wT)
{
    int idx = blockIdx.x * 256 + threadIdx.x;
    if (idx >= 18 * 256 * 7) return;
    int o = idx / 1792, rem = idx - o * 1792;
    int c = rem / 7, k = rem - c * 7;
    wT[k * 4608 + o * 256 + c] = w[idx];
}

// ---------------- K7: lrelu + conv_post (k=7,pad3) + exp/sin epilogue
__global__ __launch_bounds__(256) void k_conv_post(const float* __restrict__ mid,
    const float* __restrict__ wT, const float* __restrict__ bias, float* __restrict__ out)
{
    __shared__ float sX[256][40];
    __shared__ float wk[24 * 256];
    int b = blockIdx.y, t0 = blockIdx.x * 32;
    int tid = threadIdx.x;
    for (int r = 0; r < 38; ++r) {
        int ta = t0 - 3 + r;
        float v = 0.f;
        if (ta >= 0 && ta < 2048) v = lreluf_(mid[(size_t)(b * 2048 + ta) * 256 + tid]);
        sX[tid][r] = v;
    }
    int t = tid & 31, og = tid >> 5;
    float acc[3];
    #pragma unroll
    for (int j = 0; j < 3; j++) { int o = og + 8 * j; acc[j] = (o < 18) ? bias[o] : 0.f; }
    for (int k = 0; k < 7; ++k) {
        __syncthreads();
        for (int idx = tid; idx < 24 * 256; idx += 256)
            wk[idx] = (idx < 18 * 256) ? wT[k * 4608 + idx] : 0.f;
        __syncthreads();
        for (int c = 0; c < 256; ++c) {
            float xv = sX[c][t + k];
            acc[0] = fmaf(xv, wk[og * 256 + c], acc[0]);
            acc[1] = fmaf(xv, wk[(og + 8) * 256 + c], acc[1]);
            acc[2] = fmaf(xv, wk[(og + 16) * 256 + c], acc[2]);
        }
    }
    int ta = t0 + t;
    #pragma unroll
    for (int j = 0; j < 3; j++) {
        int o = og + 8 * j;
        if (o >= 18) continue;
        float v = acc[j];
        if (o < 9) out[(size_t)(b * 9 + o) * 2048 + ta] = __expf(v);
        else       out[73728 + (size_t)(b * 9 + (o - 9)) * 2048 + ta] = __sinf(v);
    }
}

extern "C" void kernel_launch(void* const* d_in, const int* in_sizes, int n_in,
                              void* d_out, int out_size, void* d_ws, size_t ws_size,
                              hipStream_t stream)
{
    const float* x         = (const float*)d_in[0];
    const float* pre_w     = (const float*)d_in[1];
    const float* pre_b     = (const float*)d_in[2];
    const float* inproj_w  = (const float*)d_in[3];
    const float* dw_w      = (const float*)d_in[4];
    const float* dw_b      = (const float*)d_in[5];
    const float* xproj_w   = (const float*)d_in[6];
    const float* dt_w      = (const float*)d_in[7];
    const float* dt_b      = (const float*)d_in[8];
    const float* A_log     = (const float*)d_in[9];
    const float* Dskip     = (const float*)d_in[10];
    const float* outproj_w = (const float*)d_in[11];
    const float* post_w    = (const float*)d_in[12];
    const float* post_b    = (const float*)d_in[13];
    float* out = (float*)d_out;
    float* W = (float*)d_ws;

    float* xz      = W;                 //  8,388,608 fp32
    float* uc      = W + 8388608;       //  4,194,304 fp32
    float* x_dbl   = W + 12582912;      //  1,179,648 fp32
    float* delta   = W + 13762560;      //  4,194,304 fp32 (b,t,d)-major
    float* hloc    = W + 17956864;      //  8,257,536 (63*131072; carry in-place;
                                        //             reused as out_mid after scan2f)
    float* sumd    = W + 26214400;      //    129,024 (63*2048)
    float* wTpost  = W + 26343424;      //     32,256
    unsigned short* h_bf  = (unsigned short*)(W + 26375680);  // 2,097,152 ush
    unsigned short* uc_bf = (unsigned short*)(W + 27424256);  // 4,194,304 ush
    unsigned short* g_bf  = (unsigned short*)(W + 29521408);  // 4,194,304 ush
    unsigned short* wbf_i = (unsigned short*)(W + 31618560);  //   262,144 ush
    unsigned short* wbf_x = wbf_i + 262144;                   //    73,728 ush
    unsigned short* wbf_o = wbf_x + 73728;                    //   131,072 ush
    float* out_mid = hloc;              // alias: hloc dead after scan2f

    k_pack_bf16<<<1024, 256, 0, stream>>>(inproj_w, wbf_i, 262144);
    k_pack_bf16<<<288, 256, 0, stream>>>(xproj_w, wbf_x, 73728);
    k_pack_bf16<<<512, 256, 0, stream>>>(outproj_w, wbf_o, 131072);
    k_conv_pre<<<dim3(128, 4), 256, 0, stream>>>(x, pre_w, pre_b, h_bf);
    k_gemm_mfma<0><<<dim3(16, 128), 256, 0, stream>>>(h_bf, wbf_i, xz, 8192, 1024, 256);
    k_dwconv<<<16384, 256, 0, stream>>>(xz, dw_w, dw_b, uc, uc_bf);
    k_gemm_mfma<1><<<dim3(3, 128), 256, 0, stream>>>(uc_bf, wbf_x, x_dbl, 8192, 144, 512);
    k_gemm_nt<1,0><<<dim3(8, 128), 256, 0, stream>>>(x_dbl, dt_w, dt_b, delta,
                                                     8192, 512, 16, 144, 16);
    k_scan1<<<dim3(63, 4, 4), 256, 0, stream>>>(delta, uc, x_dbl, A_log, hloc, sumd);
    k_carry<<<512, 256, 0, stream>>>(hloc, sumd, A_log);
    k_scan2f<<<dim3(64, 4, 4), 256, 0, stream>>>(delta, uc, xz, x_dbl, A_log,
                                                 hloc, Dskip, g_bf);
    k_gemm_mfma<0><<<dim3(4, 128), 256, 0, stream>>>(g_bf, wbf_o, out_mid, 8192, 256, 512);
    k_transpose_wpost<<<126, 256, 0, stream>>>(post_w, wTpost);
    k_conv_post<<<dim3(64, 4), 256, 0, stream>>>(out_mid, wTpost, post_b, out);
}